// Round 4
// baseline (661.381 us; speedup 1.0000x reference)
//
#include <hip/hip_runtime.h>
#include <hip/hip_bf16.h>

#define NN 50000      // nodes
#define NE 200000     // edges
#define NGR 500       // graphs
#define HD 128        // hidden
#define CDIM 256      // H*DH
#define NLAY 4
#define NVOC 30
#define NCAT 896      // 256*3 + 128 : Q|K|V|R concatenated
#define SCH 256                       // scan chunk
#define SNB ((NN + SCH - 1) / SCH)    // 196 scan blocks

static constexpr float BN_INV = 0.9999950000374997f;  // 1/sqrt(1+1e-5)

typedef __attribute__((ext_vector_type(8))) short bf16x8;
typedef __attribute__((ext_vector_type(4))) float f32x4;

__device__ __forceinline__ float bf2f(unsigned short u) {
    return __uint_as_float(((unsigned)u) << 16);
}
__device__ __forceinline__ unsigned short f2bf(float f) {
    union { __hip_bfloat16 h; unsigned short u; } cv;
    cv.h = __float2bfloat16(f);
    return cv.u;
}
// unpack uint4 (8 packed bf16) -> 8 floats: shl for even, and-mask for odd
__device__ __forceinline__ void up8(uint4 u, float* f) {
    f[0] = __uint_as_float(u.x << 16); f[1] = __uint_as_float(u.x & 0xffff0000u);
    f[2] = __uint_as_float(u.y << 16); f[3] = __uint_as_float(u.y & 0xffff0000u);
    f[4] = __uint_as_float(u.z << 16); f[5] = __uint_as_float(u.z & 0xffff0000u);
    f[6] = __uint_as_float(u.w << 16); f[7] = __uint_as_float(u.w & 0xffff0000u);
}

// ---------------- tables: x0table[30][128] = emb MLP (fp32) ----------------
__global__ __launch_bounds__(128) void k_tables_node(
    const float* __restrict__ ne, const float* __restrict__ w1, const float* __restrict__ b1,
    const float* __restrict__ g1, const float* __restrict__ bt1,
    const float* __restrict__ w2, const float* __restrict__ b2,
    const float* __restrict__ g0, const float* __restrict__ bt0,
    float* __restrict__ x0tab)
{
    int r = blockIdx.x, d = threadIdx.x;
    __shared__ float emb[HD], t1[HD];
    emb[d] = ne[r * HD + d];
    __syncthreads();
    float acc = b1[d];
    for (int k = 0; k < HD; ++k) acc += emb[k] * w1[k * HD + d];
    float t = fmaxf(acc * BN_INV * g1[d] + bt1[d], 0.f);
    t1[d] = t;
    __syncthreads();
    float acc2 = b2[d];
    for (int k = 0; k < HD; ++k) acc2 += t1[k] * w2[k * HD + d];
    x0tab[r * HD + d] = fmaxf(acc2 * BN_INV * g0[d] + bt0[d], 0.f);
}

// ---------------- tables: etab[l][30][256] bf16 = node_emb @ We[l] ----------------
__global__ __launch_bounds__(256) void k_tables_edge(
    const float* __restrict__ ne, const float* __restrict__ We, unsigned short* __restrict__ etab)
{
    int la = blockIdx.x;              // l*NVOC + a
    int l = la / NVOC, a = la % NVOC;
    int c = threadIdx.x;              // 0..255
    __shared__ float emb[HD];
    if (c < HD) emb[c] = ne[a * HD + c];
    __syncthreads();
    const float* W = We + (size_t)l * HD * CDIM;
    float acc = 0.f;
    for (int k = 0; k < HD; ++k) acc += emb[k] * W[k * CDIM + c];
    etab[(size_t)la * CDIM + c] = f2bf(acc);
}

// ---------------- pack weights: Wpk[l][kb][jb][lane][8] bf16 ----------------
// fragment map (both A and B operands share it): k = kb*32 + 8*(lane>>4) + t,
// j = jb*16 + (lane&15). cat columns: j<256 Wq | <512 Wk | <768 Wv | <896 Wroot
__global__ __launch_bounds__(64) void k_packw(
    const float* __restrict__ Wq, const float* __restrict__ Wk,
    const float* __restrict__ Wv, const float* __restrict__ Wr,
    unsigned short* __restrict__ Wpk)
{
    int b = blockIdx.x;               // l*224 + kb*56 + jb
    int l = b / 224, rem = b % 224;
    int kb = rem / 56, jb = rem % 56;
    int lane = threadIdx.x;
    int j = jb * 16 + (lane & 15);
    int kbase = kb * 32 + ((lane >> 4) << 3);
    unsigned short* dst = Wpk + ((size_t)b * 64 + lane) * 8;
#pragma unroll
    for (int t = 0; t < 8; ++t) {
        int k = kbase + t;
        float v;
        if (j < 256)       v = Wq[((size_t)l * HD + k) * CDIM + j];
        else if (j < 512)  v = Wk[((size_t)l * HD + k) * CDIM + (j - 256)];
        else if (j < 768)  v = Wv[((size_t)l * HD + k) * CDIM + (j - 512)];
        else               v = Wr[((size_t)l * HD + k) * HD + (j - 768)];
        dst[t] = f2bf(v);
    }
}

// ---------------- CSR build ----------------
__global__ void k_hist_dst(const int* __restrict__ ei, int* __restrict__ cnt)
{
    int e = blockIdx.x * blockDim.x + threadIdx.x;
    if (e < NE) atomicAdd(&cnt[ei[NE + e]], 1);
}

__global__ __launch_bounds__(256) void k_blocksum(const int* __restrict__ cnt, int* __restrict__ part)
{
    int t = threadIdx.x;
    int i = blockIdx.x * SCH + t;
    int v = (i < NN) ? cnt[i] : 0;
    __shared__ int sm[256];
    sm[t] = v;
    __syncthreads();
    for (int off = 128; off; off >>= 1) {
        if (t < off) sm[t] += sm[t + off];
        __syncthreads();
    }
    if (t == 0) part[blockIdx.x] = sm[0];
}

__global__ __launch_bounds__(256) void k_scanpart(int* __restrict__ part)
{
    int t = threadIdx.x;
    int v = (t < SNB) ? part[t] : 0;
    __shared__ int sm[256];
    sm[t] = v;
    __syncthreads();
    for (int off = 1; off < 256; off <<= 1) {
        int u = (t >= off) ? sm[t - off] : 0;
        __syncthreads();
        sm[t] += u;
        __syncthreads();
    }
    if (t < SNB) part[t] = sm[t] - v;   // exclusive
}

__global__ __launch_bounds__(256) void k_csrwrite(
    const int* __restrict__ cnt, const int* __restrict__ part,
    int* __restrict__ rowp, int* __restrict__ wof)
{
    int t = threadIdx.x;
    int i = blockIdx.x * SCH + t;
    int v = (i < NN) ? cnt[i] : 0;
    __shared__ int sm[256];
    sm[t] = v;
    __syncthreads();
    for (int off = 1; off < 256; off <<= 1) {
        int u = (t >= off) ? sm[t - off] : 0;
        __syncthreads();
        sm[t] += u;
        __syncthreads();
    }
    int excl = sm[t] - v + part[blockIdx.x];
    if (i < NN) { rowp[i] = excl; wof[i] = excl; }
    if (i == NN - 1) rowp[NN] = excl + v;   // = NE
}

__global__ void k_scatter(const int* __restrict__ ei, const int* __restrict__ ea,
                          int* __restrict__ wof, int* __restrict__ csrc, int* __restrict__ cea)
{
    int e = blockIdx.x * blockDim.x + threadIdx.x;
    if (e < NE) {
        int d = ei[NE + e];
        int pos = atomicAdd(&wof[d], 1);
        csrc[pos] = ei[e];
        cea[pos]  = ea[e];
    }
}

__global__ void k_gptr(const int* __restrict__ batch, int* __restrict__ gptr)
{
    int g = blockIdx.x * blockDim.x + threadIdx.x;
    if (g > NGR) return;
    if (g == NGR) { gptr[g] = NN; return; }
    int lo = 0, hi = NN;
    while (lo < hi) { int mid = (lo + hi) >> 1; if (batch[mid] < g) lo = mid + 1; else hi = mid; }
    gptr[g] = lo;
}

// ---------------- x0[n] = x0table[x[n]] (fp32 + bf16) ----------------
__global__ void k_x0(const int* __restrict__ x, const float* __restrict__ tab,
                     float* __restrict__ x0, unsigned short* __restrict__ x0b)
{
    int idx = blockIdx.x * blockDim.x + threadIdx.x;  // NN*32 float4 slots
    if (idx >= NN * 32) return;
    int n = idx >> 5, c = idx & 31;
    float4 v = *(const float4*)&tab[x[n] * HD + c * 4];
    *(float4*)&x0[(size_t)n * HD + c * 4] = v;
    ushort4 u; u.x = f2bf(v.x); u.y = f2bf(v.y); u.z = f2bf(v.z); u.w = f2bf(v.w);
    *(ushort4*)&x0b[(size_t)n * HD + c * 4] = u;
}

// ---------------- bf16 MFMA GEMM (swapped operands): D[j][node] = (W^T h)^T ----
// A-operand = W fragment (row=j), B-operand = h fragment (col=node).
// D: col=lane&15 -> node, row=4*(lane>>4)+reg -> 4 CONSECUTIVE output cols of one
// node row -> pack 2x bf16 pairs -> single 8B store.
__global__ __launch_bounds__(256) void k_gemm(
    const unsigned short* __restrict__ Ab, const unsigned short* __restrict__ Wpk,
    unsigned short* __restrict__ C)
{
    int lane = threadIdx.x & 63, wid = threadIdx.x >> 6;
    int nb = (blockIdx.x * 4 + wid) * 16;
    int node = nb + (lane & 15);
    size_t arow = (size_t)((node < NN) ? node : (NN - 1));
    int ko = (lane >> 4) << 3;
    const unsigned short* ap = Ab + arow * HD + ko;
    bf16x8 b0 = *(const bf16x8*)(ap);
    bf16x8 b1 = *(const bf16x8*)(ap + 32);
    bf16x8 b2 = *(const bf16x8*)(ap + 64);
    bf16x8 b3 = *(const bf16x8*)(ap + 96);

    const unsigned short* wp = Wpk + (size_t)lane * 8;
    bool valid = node < NN;
    int jreg = (lane >> 4) << 2;            // j offset within the 16-col block
    unsigned short* cbase = C + (size_t)node * NCAT + jreg;
#pragma unroll 2
    for (int cb = 0; cb < 56; ++cb) {
        const unsigned short* bp = wp + (size_t)cb * 512;
        bf16x8 w0 = *(const bf16x8*)(bp);
        bf16x8 w1 = *(const bf16x8*)(bp + 28672);   // kb stride = 56*512
        bf16x8 w2 = *(const bf16x8*)(bp + 57344);
        bf16x8 w3 = *(const bf16x8*)(bp + 86016);
        f32x4 acc = {0.f, 0.f, 0.f, 0.f};
        acc = __builtin_amdgcn_mfma_f32_16x16x32_bf16(w0, b0, acc, 0, 0, 0);
        acc = __builtin_amdgcn_mfma_f32_16x16x32_bf16(w1, b1, acc, 0, 0, 0);
        acc = __builtin_amdgcn_mfma_f32_16x16x32_bf16(w2, b2, acc, 0, 0, 0);
        acc = __builtin_amdgcn_mfma_f32_16x16x32_bf16(w3, b3, acc, 0, 0, 0);
        if (valid) {
            uint2 o;
            o.x = (unsigned)f2bf(acc[0]) | ((unsigned)f2bf(acc[1]) << 16);
            o.y = (unsigned)f2bf(acc[2]) | ((unsigned)f2bf(acc[3]) << 16);
            *(uint2*)(cbase + cb * 16) = o;
        }
    }
}

// ---------------- per-node attention: wave per dst node, dual edge-slots ------
// lane = slot(1b) | head(1b) | c(4b); each lane covers 8 dims (uint4 of bf16).
// Each slot runs an independent online softmax over alternating edges; slots are
// merged at the end (shfl_xor 32), then heads averaged (shfl_xor 16).
__global__ __launch_bounds__(256) void k_edge(
    const unsigned short* __restrict__ QKVR,  // [NN][896] bf16
    const unsigned short* __restrict__ etab,  // layer slice [30][256] bf16
    const float* __restrict__ attL, const float* __restrict__ biasL,
    const float* __restrict__ x0,
    const int* __restrict__ rowptr, const int* __restrict__ csrc, const int* __restrict__ cea,
    unsigned short* __restrict__ hb)          // [NN][128] bf16
{
    __shared__ unsigned etl[NVOC * CDIM / 2];          // 15360 B
    for (int i = threadIdx.x; i < NVOC * CDIM / 2; i += 256)
        etl[i] = ((const unsigned*)etab)[i];
    __syncthreads();

    int n = (blockIdx.x * blockDim.x + threadIdx.x) >> 6;
    if (n >= NN) return;
    int lane = threadIdx.x & 63;
    int c = lane & 15;
    int h = (lane >> 4) & 1;
    int slot = lane >> 5;
    int off = h * HD + c * 8;                 // dim offset within 256

    uint4 qu = *(const uint4*)&QKVR[(size_t)n * NCAT + off];
    float q[8]; up8(qu, q);
    float4 af0 = *(const float4*)(attL + off);
    float4 af1 = *(const float4*)(attL + off + 4);
    float av[8] = {af0.x, af0.y, af0.z, af0.w, af1.x, af1.y, af1.z, af1.w};

    float m = -INFINITY, lsum = 0.f;
    float acc[8] = {0.f, 0.f, 0.f, 0.f, 0.f, 0.f, 0.f, 0.f};

    int beg = rowptr[n], end = rowptr[n + 1];
    for (int idx = beg + slot; idx < end; idx += 2) {
        int s = csrc[idx], a = cea[idx];
        const unsigned short* sp = QKVR + (size_t)s * NCAT;
        uint4 ku = *(const uint4*)&sp[256 + off];
        uint4 vu = *(const uint4*)&sp[512 + off];
        uint4 eu = *(const uint4*)&etl[a * (CDIM / 2) + h * 64 + c * 4];
        float kk[8], ee[8], vv[8];
        up8(ku, kk); up8(eu, ee); up8(vu, vv);
        float p = 0.f;
#pragma unroll
        for (int i = 0; i < 8; ++i) {
            float z = q[i] + kk[i] + ee[i];
            z = (z > 0.f) ? z : 0.2f * z;
            p = fmaf(z, av[i], p);
        }
        p += __shfl_xor(p, 1); p += __shfl_xor(p, 2);
        p += __shfl_xor(p, 4); p += __shfl_xor(p, 8);
        float mn = fmaxf(m, p);
        float sc = __expf(m - mn);            // exp(-inf)=0 on first edge
        float pe = __expf(p - mn);
#pragma unroll
        for (int i = 0; i < 8; ++i) acc[i] = acc[i] * sc + pe * (vv[i] + ee[i]);
        lsum = lsum * sc + pe;
        m = mn;
    }
    // merge the two slots' online-softmax states
    float mo = __shfl_xor(m, 32);
    float lo = __shfl_xor(lsum, 32);
    float mm = fmaxf(m, mo);
    float w0 = (m  > -1e30f) ? __expf(m  - mm) : 0.f;
    float w1 = (mo > -1e30f) ? __expf(mo - mm) : 0.f;
    float L = lsum * w0 + lo * w1;
    float invl = (L > 0.f) ? 1.f / L : 0.f;
#pragma unroll
    for (int i = 0; i < 8; ++i) {
        float o = __shfl_xor(acc[i], 32);
        float v = (acc[i] * w0 + o * w1) * invl;
        acc[i] = 0.5f * (v + __shfl_xor(v, 16));   // head mean
    }
    if (lane < 16) {
        uint4 ru = *(const uint4*)&QKVR[(size_t)n * NCAT + 768 + c * 8];
        float rr[8]; up8(ru, rr);
        const float* bp = biasL + c * 8;
        const float* xp = x0 + (size_t)n * HD + c * 8;
        float4 bf0 = *(const float4*)bp, bf1 = *(const float4*)(bp + 4);
        float4 xf0 = *(const float4*)xp, xf1 = *(const float4*)(xp + 4);
        float bb[8] = {bf0.x, bf0.y, bf0.z, bf0.w, bf1.x, bf1.y, bf1.z, bf1.w};
        float xx[8] = {xf0.x, xf0.y, xf0.z, xf0.w, xf1.x, xf1.y, xf1.z, xf1.w};
        uint4 uo;
        unsigned w[4];
#pragma unroll
        for (int i = 0; i < 4; ++i) {
            float v0 = 0.9f * fmaxf(acc[2 * i]     + rr[2 * i]     + bb[2 * i],     0.f) + 0.1f * xx[2 * i];
            float v1 = 0.9f * fmaxf(acc[2 * i + 1] + rr[2 * i + 1] + bb[2 * i + 1], 0.f) + 0.1f * xx[2 * i + 1];
            w[i] = (unsigned)f2bf(v0) | ((unsigned)f2bf(v1) << 16);
        }
        uo.x = w[0]; uo.y = w[1]; uo.z = w[2]; uo.w = w[3];
        *(uint4*)&hb[(size_t)n * HD + c * 8] = uo;
    }
}

// ---------------- fused pooling: one block per graph, all 5 slices ----------------
__global__ __launch_bounds__(256) void k_poolall(
    const unsigned short* __restrict__ x0b,
    const unsigned short* __restrict__ h0, const unsigned short* __restrict__ h1,
    const unsigned short* __restrict__ h2, const unsigned short* __restrict__ h3,
    const int* __restrict__ gptr, float* __restrict__ gsum)
{
    int g = blockIdx.x;
    int t = threadIdx.x;
    int d = t & 127, half = t >> 7;
    int beg = gptr[g], end = gptr[g + 1];
    float s0 = 0.f, s1 = 0.f, s2 = 0.f, s3 = 0.f, s4 = 0.f;
    for (int n = beg + half; n < end; n += 2) {
        size_t o = (size_t)n * HD + d;
        s0 += bf2f(x0b[o]); s1 += bf2f(h0[o]); s2 += bf2f(h1[o]);
        s3 += bf2f(h2[o]);  s4 += bf2f(h3[o]);
    }
    __shared__ float sm[5][256];
    sm[0][t] = s0; sm[1][t] = s1; sm[2][t] = s2; sm[3][t] = s3; sm[4][t] = s4;
    __syncthreads();
    if (half == 0) {
#pragma unroll
        for (int sl = 0; sl < 5; ++sl)
            gsum[(size_t)g * 640 + sl * HD + d] = sm[sl][d] + sm[sl][d + 128];
    }
}

// ---------------- final MLP: g[640] -> 128 -> 1 ----------------
__global__ __launch_bounds__(128) void k_out(
    const float* __restrict__ gsum, const int* __restrict__ gptr,
    const float* __restrict__ w1, const float* __restrict__ b1,
    const float* __restrict__ g1, const float* __restrict__ bt1,
    const float* __restrict__ w2, const float* __restrict__ b2,
    float* __restrict__ out)
{
    int g = blockIdx.x, d = threadIdx.x;
    __shared__ float row[640];
    __shared__ float red[2];
    int c = gptr[g + 1] - gptr[g];
    float invc = 1.0f / (float)max(c, 1);
    for (int j = d; j < 640; j += 128) row[j] = gsum[(size_t)g * 640 + j] * invc;
    __syncthreads();
    float acc = b1[d];
    for (int j = 0; j < 640; ++j) acc += row[j] * w1[j * HD + d];
    float val = fmaxf(acc * BN_INV * g1[d] + bt1[d], 0.f);
    float part = val * w2[d];
    part += __shfl_xor(part, 32); part += __shfl_xor(part, 16);
    part += __shfl_xor(part, 8);  part += __shfl_xor(part, 4);
    part += __shfl_xor(part, 2);  part += __shfl_xor(part, 1);
    if ((threadIdx.x & 63) == 0) red[threadIdx.x >> 6] = part;
    __syncthreads();
    if (threadIdx.x == 0) out[g] = red[0] + red[1] + b2[0];
}

// ---------------- launch ----------------
extern "C" void kernel_launch(void* const* d_in, const int* in_sizes, int n_in,
                              void* d_out, int out_size, void* d_ws, size_t ws_size,
                              hipStream_t stream)
{
    const int*   x        = (const int*)d_in[0];
    const int*   ei       = (const int*)d_in[1];
    const int*   ea       = (const int*)d_in[2];
    const int*   batch    = (const int*)d_in[3];
    const float* node_emb = (const float*)d_in[4];
    const float* emb_w1   = (const float*)d_in[5];
    const float* emb_b1   = (const float*)d_in[6];
    const float* emb_g1   = (const float*)d_in[7];
    const float* emb_bt1  = (const float*)d_in[8];
    const float* emb_w2   = (const float*)d_in[9];
    const float* emb_b2   = (const float*)d_in[10];
    const float* bn0_g    = (const float*)d_in[11];
    const float* bn0_b    = (const float*)d_in[12];
    const float* Wq       = (const float*)d_in[13];
    const float* Wk       = (const float*)d_in[14];
    const float* Wv       = (const float*)d_in[15];
    const float* We       = (const float*)d_in[16];
    const float* att      = (const float*)d_in[17];
    const float* Wroot    = (const float*)d_in[18];
    const float* bias     = (const float*)d_in[19];
    const float* out_w1   = (const float*)d_in[20];
    const float* out_b1   = (const float*)d_in[21];
    const float* out_g1   = (const float*)d_in[22];
    const float* out_bt1  = (const float*)d_in[23];
    const float* out_w2   = (const float*)d_in[24];
    const float* out_b2   = (const float*)d_in[25];

    char* wp = (char*)d_ws;
    auto alloc = [&](size_t bytes) -> void* {
        void* p = (void*)wp;
        wp += (bytes + 255) & ~(size_t)255;
        return p;
    };
    float*          x0    = (float*)alloc((size_t)NN * HD * 4);
    unsigned short* x0b   = (unsigned short*)alloc((size_t)NN * HD * 2);
    unsigned short* hb0   = (unsigned short*)alloc((size_t)NN * HD * 2);
    unsigned short* hb1   = (unsigned short*)alloc((size_t)NN * HD * 2);
    unsigned short* hb2   = (unsigned short*)alloc((size_t)NN * HD * 2);
    unsigned short* hb3   = (unsigned short*)alloc((size_t)NN * HD * 2);
    unsigned short* QKVR  = (unsigned short*)alloc((size_t)NN * NCAT * 2);
    float*          x0tab = (float*)alloc((size_t)NVOC * HD * 4);
    unsigned short* etab  = (unsigned short*)alloc((size_t)NLAY * NVOC * CDIM * 2);
    unsigned short* Wpk   = (unsigned short*)alloc((size_t)NLAY * 224 * 64 * 8 * 2);
    int*   cnt   = (int*)alloc((size_t)NN * 4);
    int*   rowp  = (int*)alloc((size_t)(NN + 1) * 4);
    int*   wof   = (int*)alloc((size_t)(NN + 1) * 4);
    int*   part  = (int*)alloc((size_t)SNB * 4);
    int*   csrc  = (int*)alloc((size_t)NE * 4);
    int*   ceaB  = (int*)alloc((size_t)NE * 4);
    int*   gptr  = (int*)alloc((size_t)(NGR + 1) * 4);
    float* gsum  = (float*)alloc((size_t)NGR * 640 * 4);

    hipMemsetAsync(cnt, 0, (size_t)NN * 4, stream);

    k_tables_node<<<NVOC, 128, 0, stream>>>(node_emb, emb_w1, emb_b1, emb_g1, emb_bt1,
                                            emb_w2, emb_b2, bn0_g, bn0_b, x0tab);
    k_tables_edge<<<NLAY * NVOC, 256, 0, stream>>>(node_emb, We, etab);
    k_packw<<<NLAY * 224, 64, 0, stream>>>(Wq, Wk, Wv, Wroot, Wpk);
    k_hist_dst<<<(NE + 255) / 256, 256, 0, stream>>>(ei, cnt);
    k_blocksum<<<SNB, 256, 0, stream>>>(cnt, part);
    k_scanpart<<<1, 256, 0, stream>>>(part);
    k_csrwrite<<<SNB, 256, 0, stream>>>(cnt, part, rowp, wof);
    k_scatter<<<(NE + 255) / 256, 256, 0, stream>>>(ei, ea, wof, csrc, ceaB);
    k_gptr<<<(NGR + 1 + 255) / 256, 256, 0, stream>>>(batch, gptr);
    k_x0<<<(NN * 32 + 255) / 256, 256, 0, stream>>>(x, x0tab, x0, x0b);

    const unsigned short* hin = x0b;
    unsigned short* houts[NLAY] = {hb0, hb1, hb2, hb3};
    for (int l = 0; l < NLAY; ++l) {
        k_gemm<<<(NN + 63) / 64, 256, 0, stream>>>(hin, Wpk + (size_t)l * 224 * 512, QKVR);
        k_edge<<<(NN + 3) / 4, 256, 0, stream>>>(
            QKVR, etab + (size_t)l * NVOC * CDIM, att + (size_t)l * CDIM, bias + (size_t)l * HD,
            x0, rowp, csrc, ceaB, houts[l]);
        hin = houts[l];
    }
    k_poolall<<<NGR, 256, 0, stream>>>(x0b, hb0, hb1, hb2, hb3, gptr, gsum);
    k_out<<<NGR, 128, 0, stream>>>(gsum, gptr, out_w1, out_b1, out_g1, out_bt1,
                                   out_w2, out_b2, (float*)d_out);
}

// Round 5
// 574.455 us; speedup vs baseline: 1.1513x; 1.1513x over previous
//
#include <hip/hip_runtime.h>
#include <hip/hip_bf16.h>

#define NN 50000      // nodes
#define NE 200000     // edges
#define NGR 500       // graphs
#define HD 128        // hidden
#define CDIM 256      // H*DH
#define NLAY 4
#define NVOC 30
#define NCAT 896      // 256*3 + 128 : Q|K|V|R concatenated
#define SCH 256                       // scan chunk
#define SNB ((NN + SCH - 1) / SCH)    // 196 scan blocks

static constexpr float BN_INV = 0.9999950000374997f;  // 1/sqrt(1+1e-5)

typedef __attribute__((ext_vector_type(8))) short bf16x8;
typedef __attribute__((ext_vector_type(4))) float f32x4;

__device__ __forceinline__ float bf2f(unsigned short u) {
    return __uint_as_float(((unsigned)u) << 16);
}
__device__ __forceinline__ unsigned short f2bf(float f) {
    union { __hip_bfloat16 h; unsigned short u; } cv;
    cv.h = __float2bfloat16(f);
    return cv.u;
}

// ---------------- tables: x0table[30][128] = emb MLP (fp32) ----------------
__global__ __launch_bounds__(128) void k_tables_node(
    const float* __restrict__ ne, const float* __restrict__ w1, const float* __restrict__ b1,
    const float* __restrict__ g1, const float* __restrict__ bt1,
    const float* __restrict__ w2, const float* __restrict__ b2,
    const float* __restrict__ g0, const float* __restrict__ bt0,
    float* __restrict__ x0tab)
{
    int r = blockIdx.x, d = threadIdx.x;
    __shared__ float emb[HD], t1[HD];
    emb[d] = ne[r * HD + d];
    __syncthreads();
    float acc = b1[d];
    for (int k = 0; k < HD; ++k) acc += emb[k] * w1[k * HD + d];
    float t = fmaxf(acc * BN_INV * g1[d] + bt1[d], 0.f);
    t1[d] = t;
    __syncthreads();
    float acc2 = b2[d];
    for (int k = 0; k < HD; ++k) acc2 += t1[k] * w2[k * HD + d];
    x0tab[r * HD + d] = fmaxf(acc2 * BN_INV * g0[d] + bt0[d], 0.f);
}

// ---------------- tables: etab[l][30][256] bf16 = node_emb @ We[l] ----------------
__global__ __launch_bounds__(256) void k_tables_edge(
    const float* __restrict__ ne, const float* __restrict__ We, unsigned short* __restrict__ etab)
{
    int la = blockIdx.x;              // l*NVOC + a
    int l = la / NVOC, a = la % NVOC;
    int c = threadIdx.x;              // 0..255
    __shared__ float emb[HD];
    if (c < HD) emb[c] = ne[a * HD + c];
    __syncthreads();
    const float* W = We + (size_t)l * HD * CDIM;
    float acc = 0.f;
    for (int k = 0; k < HD; ++k) acc += emb[k] * W[k * CDIM + c];
    etab[(size_t)la * CDIM + c] = f2bf(acc);
}

// ---------------- pack weights: Wpk[l][kb][jb][lane][8] bf16 ----------------
// fragment map (both A and B operands share it): k = kb*32 + 8*(lane>>4) + t,
// j = jb*16 + (lane&15). cat columns: j<256 Wq | <512 Wk | <768 Wv | <896 Wroot
__global__ __launch_bounds__(64) void k_packw(
    const float* __restrict__ Wq, const float* __restrict__ Wk,
    const float* __restrict__ Wv, const float* __restrict__ Wr,
    unsigned short* __restrict__ Wpk)
{
    int b = blockIdx.x;               // l*224 + kb*56 + jb
    int l = b / 224, rem = b % 224;
    int kb = rem / 56, jb = rem % 56;
    int lane = threadIdx.x;
    int j = jb * 16 + (lane & 15);
    int kbase = kb * 32 + ((lane >> 4) << 3);
    unsigned short* dst = Wpk + ((size_t)b * 64 + lane) * 8;
#pragma unroll
    for (int t = 0; t < 8; ++t) {
        int k = kbase + t;
        float v;
        if (j < 256)       v = Wq[((size_t)l * HD + k) * CDIM + j];
        else if (j < 512)  v = Wk[((size_t)l * HD + k) * CDIM + (j - 256)];
        else if (j < 768)  v = Wv[((size_t)l * HD + k) * CDIM + (j - 512)];
        else               v = Wr[((size_t)l * HD + k) * HD + (j - 768)];
        dst[t] = f2bf(v);
    }
}

// ---------------- CSR build ----------------
__global__ void k_hist_dst(const int* __restrict__ ei, int* __restrict__ cnt)
{
    int e = blockIdx.x * blockDim.x + threadIdx.x;
    if (e < NE) atomicAdd(&cnt[ei[NE + e]], 1);
}

__global__ __launch_bounds__(256) void k_blocksum(const int* __restrict__ cnt, int* __restrict__ part)
{
    int t = threadIdx.x;
    int i = blockIdx.x * SCH + t;
    int v = (i < NN) ? cnt[i] : 0;
    __shared__ int sm[256];
    sm[t] = v;
    __syncthreads();
    for (int off = 128; off; off >>= 1) {
        if (t < off) sm[t] += sm[t + off];
        __syncthreads();
    }
    if (t == 0) part[blockIdx.x] = sm[0];
}

__global__ __launch_bounds__(256) void k_scanpart(int* __restrict__ part)
{
    int t = threadIdx.x;
    int v = (t < SNB) ? part[t] : 0;
    __shared__ int sm[256];
    sm[t] = v;
    __syncthreads();
    for (int off = 1; off < 256; off <<= 1) {
        int u = (t >= off) ? sm[t - off] : 0;
        __syncthreads();
        sm[t] += u;
        __syncthreads();
    }
    if (t < SNB) part[t] = sm[t] - v;   // exclusive
}

__global__ __launch_bounds__(256) void k_csrwrite(
    const int* __restrict__ cnt, const int* __restrict__ part,
    int* __restrict__ rowp, int* __restrict__ wof)
{
    int t = threadIdx.x;
    int i = blockIdx.x * SCH + t;
    int v = (i < NN) ? cnt[i] : 0;
    __shared__ int sm[256];
    sm[t] = v;
    __syncthreads();
    for (int off = 1; off < 256; off <<= 1) {
        int u = (t >= off) ? sm[t - off] : 0;
        __syncthreads();
        sm[t] += u;
        __syncthreads();
    }
    int excl = sm[t] - v + part[blockIdx.x];
    if (i < NN) { rowp[i] = excl; wof[i] = excl; }
    if (i == NN - 1) rowp[NN] = excl + v;   // = NE
}

// scatter (src, edge_attr) pairs into CSR order as int2
__global__ void k_scatter(const int* __restrict__ ei, const int* __restrict__ ea,
                          int* __restrict__ wof, int2* __restrict__ cse)
{
    int e = blockIdx.x * blockDim.x + threadIdx.x;
    if (e < NE) {
        int d = ei[NE + e];
        int pos = atomicAdd(&wof[d], 1);
        int2 v; v.x = ei[e]; v.y = ea[e];
        cse[pos] = v;
    }
}

__global__ void k_gptr(const int* __restrict__ batch, int* __restrict__ gptr)
{
    int g = blockIdx.x * blockDim.x + threadIdx.x;
    if (g > NGR) return;
    if (g == NGR) { gptr[g] = NN; return; }
    int lo = 0, hi = NN;
    while (lo < hi) { int mid = (lo + hi) >> 1; if (batch[mid] < g) lo = mid + 1; else hi = mid; }
    gptr[g] = lo;
}

// ---------------- x0[n] = x0table[x[n]] (fp32 + bf16) ----------------
__global__ void k_x0(const int* __restrict__ x, const float* __restrict__ tab,
                     float* __restrict__ x0, unsigned short* __restrict__ x0b)
{
    int idx = blockIdx.x * blockDim.x + threadIdx.x;  // NN*32 float4 slots
    if (idx >= NN * 32) return;
    int n = idx >> 5, c = idx & 31;
    float4 v = *(const float4*)&tab[x[n] * HD + c * 4];
    *(float4*)&x0[(size_t)n * HD + c * 4] = v;
    ushort4 u; u.x = f2bf(v.x); u.y = f2bf(v.y); u.z = f2bf(v.z); u.w = f2bf(v.w);
    *(ushort4*)&x0b[(size_t)n * HD + c * 4] = u;
}

// ---------------- bf16 MFMA GEMM (swapped operands): D[j][node] = (W^T h)^T ----
// A-operand = W fragment (row=j), B-operand = h fragment (col=node).
// D: col=lane&15 -> node, row=4*(lane>>4)+reg -> 4 CONSECUTIVE output cols of one
// node row -> pack 2x bf16 pairs -> single 8B store.
__global__ __launch_bounds__(256) void k_gemm(
    const unsigned short* __restrict__ Ab, const unsigned short* __restrict__ Wpk,
    unsigned short* __restrict__ C)
{
    int lane = threadIdx.x & 63, wid = threadIdx.x >> 6;
    int nb = (blockIdx.x * 4 + wid) * 16;
    int node = nb + (lane & 15);
    size_t arow = (size_t)((node < NN) ? node : (NN - 1));
    int ko = (lane >> 4) << 3;
    const unsigned short* ap = Ab + arow * HD + ko;
    bf16x8 b0 = *(const bf16x8*)(ap);
    bf16x8 b1 = *(const bf16x8*)(ap + 32);
    bf16x8 b2 = *(const bf16x8*)(ap + 64);
    bf16x8 b3 = *(const bf16x8*)(ap + 96);

    const unsigned short* wp = Wpk + (size_t)lane * 8;
    bool valid = node < NN;
    int jreg = (lane >> 4) << 2;            // j offset within the 16-col block
    unsigned short* cbase = C + (size_t)node * NCAT + jreg;
#pragma unroll 2
    for (int cb = 0; cb < 56; ++cb) {
        const unsigned short* bp = wp + (size_t)cb * 512;
        bf16x8 w0 = *(const bf16x8*)(bp);
        bf16x8 w1 = *(const bf16x8*)(bp + 28672);   // kb stride = 56*512
        bf16x8 w2 = *(const bf16x8*)(bp + 57344);
        bf16x8 w3 = *(const bf16x8*)(bp + 86016);
        f32x4 acc = {0.f, 0.f, 0.f, 0.f};
        acc = __builtin_amdgcn_mfma_f32_16x16x32_bf16(w0, b0, acc, 0, 0, 0);
        acc = __builtin_amdgcn_mfma_f32_16x16x32_bf16(w1, b1, acc, 0, 0, 0);
        acc = __builtin_amdgcn_mfma_f32_16x16x32_bf16(w2, b2, acc, 0, 0, 0);
        acc = __builtin_amdgcn_mfma_f32_16x16x32_bf16(w3, b3, acc, 0, 0, 0);
        if (valid) {
            uint2 o;
            o.x = (unsigned)f2bf(acc[0]) | ((unsigned)f2bf(acc[1]) << 16);
            o.y = (unsigned)f2bf(acc[2]) | ((unsigned)f2bf(acc[3]) << 16);
            *(uint2*)(cbase + cb * 16) = o;
        }
    }
}

// ---------------- per-node attention: wave per dst node (R3 shape) -----------
// lane = head(1b) | sub(5b); 4 dims/lane. Softmax without max-subtraction:
// exp(p)/sum(exp(p)) == ref's exp(p-max)/sum(exp(p-max)). |p| << 1 at this data
// scale; clamp to +-30 for overflow safety (pass-through in realistic range).
// Removes the serial online-softmax rescale chain entirely.
__global__ __launch_bounds__(256) void k_edge(
    const unsigned short* __restrict__ QKVR,  // [NN][896] bf16
    const unsigned short* __restrict__ etab,  // layer slice [30][256] bf16
    const float* __restrict__ attL, const float* __restrict__ biasL,
    const float* __restrict__ x0,
    const int* __restrict__ rowptr, const int2* __restrict__ cse,
    unsigned short* __restrict__ hb)          // [NN][128] bf16
{
    int n = (blockIdx.x * blockDim.x + threadIdx.x) >> 6;
    if (n >= NN) return;
    int lane = threadIdx.x & 63;
    int head = lane >> 5, sub = lane & 31;
    int col = head * HD + sub * 4;

    ushort4 qu = *(const ushort4*)&QKVR[(size_t)n * NCAT + col];
    float qx = bf2f(qu.x), qy = bf2f(qu.y), qz = bf2f(qu.z), qw = bf2f(qu.w);
    float4 a4 = *(const float4*)&attL[col];

    float l = 0.f;
    float4 acc = {0.f, 0.f, 0.f, 0.f};

    int beg = rowptr[n], end = rowptr[n + 1];
    for (int idx = beg; idx < end; ++idx) {
        int2 se = cse[idx];
        int s = se.x, a = se.y;
        const unsigned short* sp = QKVR + (size_t)s * NCAT;
        ushort4 ku = *(const ushort4*)&sp[256 + col];
        ushort4 eu = *(const ushort4*)&etab[a * CDIM + col];
        ushort4 vu = *(const ushort4*)&sp[512 + col];
        float ex = bf2f(eu.x), ey = bf2f(eu.y), ez = bf2f(eu.z), ew = bf2f(eu.w);
        float zx = qx + bf2f(ku.x) + ex; zx = (zx > 0.f) ? zx : 0.2f * zx;
        float zy = qy + bf2f(ku.y) + ey; zy = (zy > 0.f) ? zy : 0.2f * zy;
        float zz = qz + bf2f(ku.z) + ez; zz = (zz > 0.f) ? zz : 0.2f * zz;
        float zw = qw + bf2f(ku.w) + ew; zw = (zw > 0.f) ? zw : 0.2f * zw;
        float p = zx * a4.x + zy * a4.y + zz * a4.z + zw * a4.w;
        p += __shfl_xor(p, 16); p += __shfl_xor(p, 8);
        p += __shfl_xor(p, 4);  p += __shfl_xor(p, 2); p += __shfl_xor(p, 1);
        float pe = __expf(fminf(fmaxf(p, -30.f), 30.f));
        acc.x = fmaf(pe, bf2f(vu.x) + ex, acc.x);
        acc.y = fmaf(pe, bf2f(vu.y) + ey, acc.y);
        acc.z = fmaf(pe, bf2f(vu.z) + ez, acc.z);
        acc.w = fmaf(pe, bf2f(vu.w) + ew, acc.w);
        l += pe;
    }
    float invl = (l > 0.f) ? 1.0f / l : 0.f;
    float ax = acc.x * invl, ay = acc.y * invl, az = acc.z * invl, aw = acc.w * invl;
    // mean over heads: pair lane <-> lane^32
    ax = 0.5f * (ax + __shfl_xor(ax, 32));
    ay = 0.5f * (ay + __shfl_xor(ay, 32));
    az = 0.5f * (az + __shfl_xor(az, 32));
    aw = 0.5f * (aw + __shfl_xor(aw, 32));
    if (head == 0) {
        ushort4 ru = *(const ushort4*)&QKVR[(size_t)n * NCAT + 768 + sub * 4];
        float4 b4 = *(const float4*)&biasL[sub * 4];
        float4 x4 = *(const float4*)&x0[(size_t)n * HD + sub * 4];
        float ox = 0.9f * fmaxf(ax + bf2f(ru.x) + b4.x, 0.f) + 0.1f * x4.x;
        float oy = 0.9f * fmaxf(ay + bf2f(ru.y) + b4.y, 0.f) + 0.1f * x4.y;
        float oz = 0.9f * fmaxf(az + bf2f(ru.z) + b4.z, 0.f) + 0.1f * x4.z;
        float ow = 0.9f * fmaxf(aw + bf2f(ru.w) + b4.w, 0.f) + 0.1f * x4.w;
        ushort4 o; o.x = f2bf(ox); o.y = f2bf(oy); o.z = f2bf(oz); o.w = f2bf(ow);
        *(ushort4*)&hb[(size_t)n * HD + sub * 4] = o;
    }
}

// ---------------- fused pooling: one block per graph, all 5 slices ----------------
__global__ __launch_bounds__(256) void k_poolall(
    const unsigned short* __restrict__ x0b,
    const unsigned short* __restrict__ h0, const unsigned short* __restrict__ h1,
    const unsigned short* __restrict__ h2, const unsigned short* __restrict__ h3,
    const int* __restrict__ gptr, float* __restrict__ gsum)
{
    int g = blockIdx.x;
    int t = threadIdx.x;
    int d = t & 127, half = t >> 7;
    int beg = gptr[g], end = gptr[g + 1];
    float s0 = 0.f, s1 = 0.f, s2 = 0.f, s3 = 0.f, s4 = 0.f;
    for (int n = beg + half; n < end; n += 2) {
        size_t o = (size_t)n * HD + d;
        s0 += bf2f(x0b[o]); s1 += bf2f(h0[o]); s2 += bf2f(h1[o]);
        s3 += bf2f(h2[o]);  s4 += bf2f(h3[o]);
    }
    __shared__ float sm[5][256];
    sm[0][t] = s0; sm[1][t] = s1; sm[2][t] = s2; sm[3][t] = s3; sm[4][t] = s4;
    __syncthreads();
    if (half == 0) {
#pragma unroll
        for (int sl = 0; sl < 5; ++sl)
            gsum[(size_t)g * 640 + sl * HD + d] = sm[sl][d] + sm[sl][d + 128];
    }
}

// ---------------- final MLP: g[640] -> 128 -> 1 ----------------
__global__ __launch_bounds__(128) void k_out(
    const float* __restrict__ gsum, const int* __restrict__ gptr,
    const float* __restrict__ w1, const float* __restrict__ b1,
    const float* __restrict__ g1, const float* __restrict__ bt1,
    const float* __restrict__ w2, const float* __restrict__ b2,
    float* __restrict__ out)
{
    int g = blockIdx.x, d = threadIdx.x;
    __shared__ float row[640];
    __shared__ float red[2];
    int c = gptr[g + 1] - gptr[g];
    float invc = 1.0f / (float)max(c, 1);
    for (int j = d; j < 640; j += 128) row[j] = gsum[(size_t)g * 640 + j] * invc;
    __syncthreads();
    float acc = b1[d];
    for (int j = 0; j < 640; ++j) acc += row[j] * w1[j * HD + d];
    float val = fmaxf(acc * BN_INV * g1[d] + bt1[d], 0.f);
    float part = val * w2[d];
    part += __shfl_xor(part, 32); part += __shfl_xor(part, 16);
    part += __shfl_xor(part, 8);  part += __shfl_xor(part, 4);
    part += __shfl_xor(part, 2);  part += __shfl_xor(part, 1);
    if ((threadIdx.x & 63) == 0) red[threadIdx.x >> 6] = part;
    __syncthreads();
    if (threadIdx.x == 0) out[g] = red[0] + red[1] + b2[0];
}

// ---------------- launch ----------------
extern "C" void kernel_launch(void* const* d_in, const int* in_sizes, int n_in,
                              void* d_out, int out_size, void* d_ws, size_t ws_size,
                              hipStream_t stream)
{
    const int*   x        = (const int*)d_in[0];
    const int*   ei       = (const int*)d_in[1];
    const int*   ea       = (const int*)d_in[2];
    const int*   batch    = (const int*)d_in[3];
    const float* node_emb = (const float*)d_in[4];
    const float* emb_w1   = (const float*)d_in[5];
    const float* emb_b1   = (const float*)d_in[6];
    const float* emb_g1   = (const float*)d_in[7];
    const float* emb_bt1  = (const float*)d_in[8];
    const float* emb_w2   = (const float*)d_in[9];
    const float* emb_b2   = (const float*)d_in[10];
    const float* bn0_g    = (const float*)d_in[11];
    const float* bn0_b    = (const float*)d_in[12];
    const float* Wq       = (const float*)d_in[13];
    const float* Wk       = (const float*)d_in[14];
    const float* Wv       = (const float*)d_in[15];
    const float* We       = (const float*)d_in[16];
    const float* att      = (const float*)d_in[17];
    const float* Wroot    = (const float*)d_in[18];
    const float* bias     = (const float*)d_in[19];
    const float* out_w1   = (const float*)d_in[20];
    const float* out_b1   = (const float*)d_in[21];
    const float* out_g1   = (const float*)d_in[22];
    const float* out_bt1  = (const float*)d_in[23];
    const float* out_w2   = (const float*)d_in[24];
    const float* out_b2   = (const float*)d_in[25];

    char* wp = (char*)d_ws;
    auto alloc = [&](size_t bytes) -> void* {
        void* p = (void*)wp;
        wp += (bytes + 255) & ~(size_t)255;
        return p;
    };
    float*          x0    = (float*)alloc((size_t)NN * HD * 4);
    unsigned short* x0b   = (unsigned short*)alloc((size_t)NN * HD * 2);
    unsigned short* hb0   = (unsigned short*)alloc((size_t)NN * HD * 2);
    unsigned short* hb1   = (unsigned short*)alloc((size_t)NN * HD * 2);
    unsigned short* hb2   = (unsigned short*)alloc((size_t)NN * HD * 2);
    unsigned short* hb3   = (unsigned short*)alloc((size_t)NN * HD * 2);
    unsigned short* QKVR  = (unsigned short*)alloc((size_t)NN * NCAT * 2);
    float*          x0tab = (float*)alloc((size_t)NVOC * HD * 4);
    unsigned short* etab  = (unsigned short*)alloc((size_t)NLAY * NVOC * CDIM * 2);
    unsigned short* Wpk   = (unsigned short*)alloc((size_t)NLAY * 224 * 64 * 8 * 2);
    int*   cnt   = (int*)alloc((size_t)NN * 4);
    int*   rowp  = (int*)alloc((size_t)(NN + 1) * 4);
    int*   wof   = (int*)alloc((size_t)(NN + 1) * 4);
    int*   part  = (int*)alloc((size_t)SNB * 4);
    int2*  cse   = (int2*)alloc((size_t)NE * 8);
    int*   gptr  = (int*)alloc((size_t)(NGR + 1) * 4);
    float* gsum  = (float*)alloc((size_t)NGR * 640 * 4);

    hipMemsetAsync(cnt, 0, (size_t)NN * 4, stream);

    k_tables_node<<<NVOC, 128, 0, stream>>>(node_emb, emb_w1, emb_b1, emb_g1, emb_bt1,
                                            emb_w2, emb_b2, bn0_g, bn0_b, x0tab);
    k_tables_edge<<<NLAY * NVOC, 256, 0, stream>>>(node_emb, We, etab);
    k_packw<<<NLAY * 224, 64, 0, stream>>>(Wq, Wk, Wv, Wroot, Wpk);
    k_hist_dst<<<(NE + 255) / 256, 256, 0, stream>>>(ei, cnt);
    k_blocksum<<<SNB, 256, 0, stream>>>(cnt, part);
    k_scanpart<<<1, 256, 0, stream>>>(part);
    k_csrwrite<<<SNB, 256, 0, stream>>>(cnt, part, rowp, wof);
    k_scatter<<<(NE + 255) / 256, 256, 0, stream>>>(ei, ea, wof, cse);
    k_gptr<<<(NGR + 1 + 255) / 256, 256, 0, stream>>>(batch, gptr);
    k_x0<<<(NN * 32 + 255) / 256, 256, 0, stream>>>(x, x0tab, x0, x0b);

    const unsigned short* hin = x0b;
    unsigned short* houts[NLAY] = {hb0, hb1, hb2, hb3};
    for (int l = 0; l < NLAY; ++l) {
        k_gemm<<<(NN + 63) / 64, 256, 0, stream>>>(hin, Wpk + (size_t)l * 224 * 512, QKVR);
        k_edge<<<(NN * 64 + 255) / 256, 256, 0, stream>>>(
            QKVR, etab + (size_t)l * NVOC * CDIM, att + (size_t)l * CDIM, bias + (size_t)l * HD,
            x0, rowp, cse, houts[l]);
        hin = houts[l];
    }
    k_poolall<<<NGR, 256, 0, stream>>>(x0b, hb0, hb1, hb2, hb3, gptr, gsum);
    k_out<<<NGR, 128, 0, stream>>>(gsum, gptr, out_w1, out_b1, out_g1, out_bt1,
                                   out_w2, out_b2, (float*)d_out);
}

// Round 6
// 541.342 us; speedup vs baseline: 1.2217x; 1.0612x over previous
//
#include <hip/hip_runtime.h>
#include <hip/hip_bf16.h>

#define NN 50000      // nodes
#define NE 200000     // edges
#define NGR 500       // graphs
#define HD 128        // hidden
#define CDIM 256      // H*DH
#define NLAY 4
#define NVOC 30
#define NCAT 896      // 256*3 + 128 : Q|K|V|R concatenated
#define SCH 256                       // scan chunk
#define SNB ((NN + SCH - 1) / SCH)    // 196 scan blocks
#define GP 4                          // gemm column panels
#define CBP (56 / GP)                 // cb iters per panel = 14

static constexpr float BN_INV = 0.9999950000374997f;  // 1/sqrt(1+1e-5)

typedef __attribute__((ext_vector_type(8))) short bf16x8;
typedef __attribute__((ext_vector_type(4))) float f32x4;

__device__ __forceinline__ float bf2f(unsigned short u) {
    return __uint_as_float(((unsigned)u) << 16);
}
__device__ __forceinline__ unsigned short f2bf(float f) {
    union { __hip_bfloat16 h; unsigned short u; } cv;
    cv.h = __float2bfloat16(f);
    return cv.u;
}

// ---------------- tables: x0table[30][128] = emb MLP (fp32) ----------------
__global__ __launch_bounds__(128) void k_tables_node(
    const float* __restrict__ ne, const float* __restrict__ w1, const float* __restrict__ b1,
    const float* __restrict__ g1, const float* __restrict__ bt1,
    const float* __restrict__ w2, const float* __restrict__ b2,
    const float* __restrict__ g0, const float* __restrict__ bt0,
    float* __restrict__ x0tab)
{
    int r = blockIdx.x, d = threadIdx.x;
    __shared__ float emb[HD], t1[HD];
    emb[d] = ne[r * HD + d];
    __syncthreads();
    float acc = b1[d];
    for (int k = 0; k < HD; ++k) acc += emb[k] * w1[k * HD + d];
    float t = fmaxf(acc * BN_INV * g1[d] + bt1[d], 0.f);
    t1[d] = t;
    __syncthreads();
    float acc2 = b2[d];
    for (int k = 0; k < HD; ++k) acc2 += t1[k] * w2[k * HD + d];
    x0tab[r * HD + d] = fmaxf(acc2 * BN_INV * g0[d] + bt0[d], 0.f);
}

// ---------------- tables: etab[l][30][256] bf16 = node_emb @ We[l] ----------------
__global__ __launch_bounds__(256) void k_tables_edge(
    const float* __restrict__ ne, const float* __restrict__ We, unsigned short* __restrict__ etab)
{
    int la = blockIdx.x;              // l*NVOC + a
    int l = la / NVOC, a = la % NVOC;
    int c = threadIdx.x;              // 0..255
    __shared__ float emb[HD];
    if (c < HD) emb[c] = ne[a * HD + c];
    __syncthreads();
    const float* W = We + (size_t)l * HD * CDIM;
    float acc = 0.f;
    for (int k = 0; k < HD; ++k) acc += emb[k] * W[k * CDIM + c];
    etab[(size_t)la * CDIM + c] = f2bf(acc);
}

// ---------------- pack weights: Wpk[l][kb][jb][lane][8] bf16 ----------------
// fragment map (both A and B operands share it): k = kb*32 + 8*(lane>>4) + t,
// j = jb*16 + (lane&15). cat columns: j<256 Wq | <512 Wk | <768 Wv | <896 Wroot
__global__ __launch_bounds__(64) void k_packw(
    const float* __restrict__ Wq, const float* __restrict__ Wk,
    const float* __restrict__ Wv, const float* __restrict__ Wr,
    unsigned short* __restrict__ Wpk)
{
    int b = blockIdx.x;               // l*224 + kb*56 + jb
    int l = b / 224, rem = b % 224;
    int kb = rem / 56, jb = rem % 56;
    int lane = threadIdx.x;
    int j = jb * 16 + (lane & 15);
    int kbase = kb * 32 + ((lane >> 4) << 3);
    unsigned short* dst = Wpk + ((size_t)b * 64 + lane) * 8;
#pragma unroll
    for (int t = 0; t < 8; ++t) {
        int k = kbase + t;
        float v;
        if (j < 256)       v = Wq[((size_t)l * HD + k) * CDIM + j];
        else if (j < 512)  v = Wk[((size_t)l * HD + k) * CDIM + (j - 256)];
        else if (j < 768)  v = Wv[((size_t)l * HD + k) * CDIM + (j - 512)];
        else               v = Wr[((size_t)l * HD + k) * HD + (j - 768)];
        dst[t] = f2bf(v);
    }
}

// ---------------- CSR build ----------------
__global__ void k_hist_dst(const int* __restrict__ ei, int* __restrict__ cnt)
{
    int e = blockIdx.x * blockDim.x + threadIdx.x;
    if (e < NE) atomicAdd(&cnt[ei[NE + e]], 1);
}

__global__ __launch_bounds__(256) void k_blocksum(const int* __restrict__ cnt, int* __restrict__ part)
{
    int t = threadIdx.x;
    int i = blockIdx.x * SCH + t;
    int v = (i < NN) ? cnt[i] : 0;
    __shared__ int sm[256];
    sm[t] = v;
    __syncthreads();
    for (int off = 128; off; off >>= 1) {
        if (t < off) sm[t] += sm[t + off];
        __syncthreads();
    }
    if (t == 0) part[blockIdx.x] = sm[0];
}

__global__ __launch_bounds__(256) void k_scanpart(int* __restrict__ part)
{
    int t = threadIdx.x;
    int v = (t < SNB) ? part[t] : 0;
    __shared__ int sm[256];
    sm[t] = v;
    __syncthreads();
    for (int off = 1; off < 256; off <<= 1) {
        int u = (t >= off) ? sm[t - off] : 0;
        __syncthreads();
        sm[t] += u;
        __syncthreads();
    }
    if (t < SNB) part[t] = sm[t] - v;   // exclusive
}

__global__ __launch_bounds__(256) void k_csrwrite(
    const int* __restrict__ cnt, const int* __restrict__ part,
    int* __restrict__ rowp, int* __restrict__ wof)
{
    int t = threadIdx.x;
    int i = blockIdx.x * SCH + t;
    int v = (i < NN) ? cnt[i] : 0;
    __shared__ int sm[256];
    sm[t] = v;
    __syncthreads();
    for (int off = 1; off < 256; off <<= 1) {
        int u = (t >= off) ? sm[t - off] : 0;
        __syncthreads();
        sm[t] += u;
        __syncthreads();
    }
    int excl = sm[t] - v + part[blockIdx.x];
    if (i < NN) { rowp[i] = excl; wof[i] = excl; }
    if (i == NN - 1) rowp[NN] = excl + v;   // = NE
}

// scatter (src, edge_attr) pairs into CSR order as int2
__global__ void k_scatter(const int* __restrict__ ei, const int* __restrict__ ea,
                          int* __restrict__ wof, int2* __restrict__ cse)
{
    int e = blockIdx.x * blockDim.x + threadIdx.x;
    if (e < NE) {
        int d = ei[NE + e];
        int pos = atomicAdd(&wof[d], 1);
        int2 v; v.x = ei[e]; v.y = ea[e];
        cse[pos] = v;
    }
}

__global__ void k_gptr(const int* __restrict__ batch, int* __restrict__ gptr)
{
    int g = blockIdx.x * blockDim.x + threadIdx.x;
    if (g > NGR) return;
    if (g == NGR) { gptr[g] = NN; return; }
    int lo = 0, hi = NN;
    while (lo < hi) { int mid = (lo + hi) >> 1; if (batch[mid] < g) lo = mid + 1; else hi = mid; }
    gptr[g] = lo;
}

// ---------------- x0[n] = x0table[x[n]] (fp32 + bf16) ----------------
__global__ void k_x0(const int* __restrict__ x, const float* __restrict__ tab,
                     float* __restrict__ x0, unsigned short* __restrict__ x0b)
{
    int idx = blockIdx.x * blockDim.x + threadIdx.x;  // NN*32 float4 slots
    if (idx >= NN * 32) return;
    int n = idx >> 5, c = idx & 31;
    float4 v = *(const float4*)&tab[x[n] * HD + c * 4];
    *(float4*)&x0[(size_t)n * HD + c * 4] = v;
    ushort4 u; u.x = f2bf(v.x); u.y = f2bf(v.y); u.z = f2bf(v.z); u.w = f2bf(v.w);
    *(ushort4*)&x0b[(size_t)n * HD + c * 4] = u;
}

// ---------------- bf16 MFMA GEMM (swapped operands): D[j][node] = (W^T h)^T ----
// A-operand = W fragment (row=j), B-operand = h fragment (col=node).
// D: col=lane&15 -> node, row=4*(lane>>4)+reg -> 4 CONSECUTIVE output cols of one
// node row -> pack 2x bf16 pairs -> single 8B store.
// grid.y = GP column panels (CBP cb-iters each) for occupancy: 782 blocks was
// 24% occupancy, latency-bound (R5 counters).
__global__ __launch_bounds__(256) void k_gemm(
    const unsigned short* __restrict__ Ab, const unsigned short* __restrict__ Wpk,
    unsigned short* __restrict__ C)
{
    int lane = threadIdx.x & 63, wid = threadIdx.x >> 6;
    int nb = (blockIdx.x * 4 + wid) * 16;
    int node = nb + (lane & 15);
    size_t arow = (size_t)((node < NN) ? node : (NN - 1));
    int ko = (lane >> 4) << 3;
    const unsigned short* ap = Ab + arow * HD + ko;
    bf16x8 b0 = *(const bf16x8*)(ap);
    bf16x8 b1 = *(const bf16x8*)(ap + 32);
    bf16x8 b2 = *(const bf16x8*)(ap + 64);
    bf16x8 b3 = *(const bf16x8*)(ap + 96);

    const unsigned short* wp = Wpk + (size_t)lane * 8;
    bool valid = node < NN;
    int jreg = (lane >> 4) << 2;            // j offset within the 16-col block
    unsigned short* cbase = C + (size_t)node * NCAT + jreg;
    int cb0 = blockIdx.y * CBP;
#pragma unroll 2
    for (int cb = cb0; cb < cb0 + CBP; ++cb) {
        const unsigned short* bp = wp + (size_t)cb * 512;
        bf16x8 w0 = *(const bf16x8*)(bp);
        bf16x8 w1 = *(const bf16x8*)(bp + 28672);   // kb stride = 56*512
        bf16x8 w2 = *(const bf16x8*)(bp + 57344);
        bf16x8 w3 = *(const bf16x8*)(bp + 86016);
        f32x4 acc = {0.f, 0.f, 0.f, 0.f};
        acc = __builtin_amdgcn_mfma_f32_16x16x32_bf16(w0, b0, acc, 0, 0, 0);
        acc = __builtin_amdgcn_mfma_f32_16x16x32_bf16(w1, b1, acc, 0, 0, 0);
        acc = __builtin_amdgcn_mfma_f32_16x16x32_bf16(w2, b2, acc, 0, 0, 0);
        acc = __builtin_amdgcn_mfma_f32_16x16x32_bf16(w3, b3, acc, 0, 0, 0);
        if (valid) {
            uint2 o;
            o.x = (unsigned)f2bf(acc[0]) | ((unsigned)f2bf(acc[1]) << 16);
            o.y = (unsigned)f2bf(acc[2]) | ((unsigned)f2bf(acc[3]) << 16);
            *(uint2*)(cbase + cb * 16) = o;
        }
    }
}

// ---------------- per-node attention: wave per dst node -----------
// lane = head(1b) | sub(5b); 4 dims/lane. Softmax without max-subtraction:
// exp(p)/sum(exp(p)) == ref's exp(p-max)/sum(exp(p-max)). |p| << 1 at this data
// scale; clamp to +-30 for overflow safety (pass-through in realistic range).
__global__ __launch_bounds__(256) void k_edge(
    const unsigned short* __restrict__ QKVR,  // [NN][896] bf16
    const unsigned short* __restrict__ etab,  // layer slice [30][256] bf16
    const float* __restrict__ attL, const float* __restrict__ biasL,
    const float* __restrict__ x0,
    const int* __restrict__ rowptr, const int2* __restrict__ cse,
    unsigned short* __restrict__ hb)          // [NN][128] bf16
{
    int n = (blockIdx.x * blockDim.x + threadIdx.x) >> 6;
    if (n >= NN) return;
    int lane = threadIdx.x & 63;
    int head = lane >> 5, sub = lane & 31;
    int col = head * HD + sub * 4;

    ushort4 qu = *(const ushort4*)&QKVR[(size_t)n * NCAT + col];
    float qx = bf2f(qu.x), qy = bf2f(qu.y), qz = bf2f(qu.z), qw = bf2f(qu.w);
    float4 a4 = *(const float4*)&attL[col];

    float l = 0.f;
    float4 acc = {0.f, 0.f, 0.f, 0.f};

    int beg = rowptr[n], end = rowptr[n + 1];
    for (int idx = beg; idx < end; ++idx) {
        int2 se = cse[idx];
        int s = se.x, a = se.y;
        const unsigned short* sp = QKVR + (size_t)s * NCAT;
        ushort4 ku = *(const ushort4*)&sp[256 + col];
        ushort4 eu = *(const ushort4*)&etab[a * CDIM + col];
        ushort4 vu = *(const ushort4*)&sp[512 + col];
        float ex = bf2f(eu.x), ey = bf2f(eu.y), ez = bf2f(eu.z), ew = bf2f(eu.w);
        float zx = qx + bf2f(ku.x) + ex; zx = (zx > 0.f) ? zx : 0.2f * zx;
        float zy = qy + bf2f(ku.y) + ey; zy = (zy > 0.f) ? zy : 0.2f * zy;
        float zz = qz + bf2f(ku.z) + ez; zz = (zz > 0.f) ? zz : 0.2f * zz;
        float zw = qw + bf2f(ku.w) + ew; zw = (zw > 0.f) ? zw : 0.2f * zw;
        float p = zx * a4.x + zy * a4.y + zz * a4.z + zw * a4.w;
        p += __shfl_xor(p, 16); p += __shfl_xor(p, 8);
        p += __shfl_xor(p, 4);  p += __shfl_xor(p, 2); p += __shfl_xor(p, 1);
        float pe = __expf(fminf(fmaxf(p, -30.f), 30.f));
        acc.x = fmaf(pe, bf2f(vu.x) + ex, acc.x);
        acc.y = fmaf(pe, bf2f(vu.y) + ey, acc.y);
        acc.z = fmaf(pe, bf2f(vu.z) + ez, acc.z);
        acc.w = fmaf(pe, bf2f(vu.w) + ew, acc.w);
        l += pe;
    }
    float invl = (l > 0.f) ? 1.0f / l : 0.f;
    float ax = acc.x * invl, ay = acc.y * invl, az = acc.z * invl, aw = acc.w * invl;
    // mean over heads: pair lane <-> lane^32
    ax = 0.5f * (ax + __shfl_xor(ax, 32));
    ay = 0.5f * (ay + __shfl_xor(ay, 32));
    az = 0.5f * (az + __shfl_xor(az, 32));
    aw = 0.5f * (aw + __shfl_xor(aw, 32));
    if (head == 0) {
        ushort4 ru = *(const ushort4*)&QKVR[(size_t)n * NCAT + 768 + sub * 4];
        float4 b4 = *(const float4*)&biasL[sub * 4];
        float4 x4 = *(const float4*)&x0[(size_t)n * HD + sub * 4];
        float ox = 0.9f * fmaxf(ax + bf2f(ru.x) + b4.x, 0.f) + 0.1f * x4.x;
        float oy = 0.9f * fmaxf(ay + bf2f(ru.y) + b4.y, 0.f) + 0.1f * x4.y;
        float oz = 0.9f * fmaxf(az + bf2f(ru.z) + b4.z, 0.f) + 0.1f * x4.z;
        float ow = 0.9f * fmaxf(aw + bf2f(ru.w) + b4.w, 0.f) + 0.1f * x4.w;
        ushort4 o; o.x = f2bf(ox); o.y = f2bf(oy); o.z = f2bf(oz); o.w = f2bf(ow);
        *(ushort4*)&hb[(size_t)n * HD + sub * 4] = o;
    }
}

// ---------------- fused pooling: one block per graph, all 5 slices ----------------
__global__ __launch_bounds__(256) void k_poolall(
    const unsigned short* __restrict__ x0b,
    const unsigned short* __restrict__ h0, const unsigned short* __restrict__ h1,
    const unsigned short* __restrict__ h2, const unsigned short* __restrict__ h3,
    const int* __restrict__ gptr, float* __restrict__ gsum)
{
    int g = blockIdx.x;
    int t = threadIdx.x;
    int d = t & 127, half = t >> 7;
    int beg = gptr[g], end = gptr[g + 1];
    float s0 = 0.f, s1 = 0.f, s2 = 0.f, s3 = 0.f, s4 = 0.f;
    for (int n = beg + half; n < end; n += 2) {
        size_t o = (size_t)n * HD + d;
        s0 += bf2f(x0b[o]); s1 += bf2f(h0[o]); s2 += bf2f(h1[o]);
        s3 += bf2f(h2[o]);  s4 += bf2f(h3[o]);
    }
    __shared__ float sm[5][256];
    sm[0][t] = s0; sm[1][t] = s1; sm[2][t] = s2; sm[3][t] = s3; sm[4][t] = s4;
    __syncthreads();
    if (half == 0) {
#pragma unroll
        for (int sl = 0; sl < 5; ++sl)
            gsum[(size_t)g * 640 + sl * HD + d] = sm[sl][d] + sm[sl][d + 128];
    }
}

// ---------------- final MLP: g[640] -> 128 -> 1 ----------------
__global__ __launch_bounds__(128) void k_out(
    const float* __restrict__ gsum, const int* __restrict__ gptr,
    const float* __restrict__ w1, const float* __restrict__ b1,
    const float* __restrict__ g1, const float* __restrict__ bt1,
    const float* __restrict__ w2, const float* __restrict__ b2,
    float* __restrict__ out)
{
    int g = blockIdx.x, d = threadIdx.x;
    __shared__ float row[640];
    __shared__ float red[2];
    int c = gptr[g + 1] - gptr[g];
    float invc = 1.0f / (float)max(c, 1);
    for (int j = d; j < 640; j += 128) row[j] = gsum[(size_t)g * 640 + j] * invc;
    __syncthreads();
    float acc = b1[d];
    for (int j = 0; j < 640; ++j) acc += row[j] * w1[j * HD + d];
    float val = fmaxf(acc * BN_INV * g1[d] + bt1[d], 0.f);
    float part = val * w2[d];
    part += __shfl_xor(part, 32); part += __shfl_xor(part, 16);
    part += __shfl_xor(part, 8);  part += __shfl_xor(part, 4);
    part += __shfl_xor(part, 2);  part += __shfl_xor(part, 1);
    if ((threadIdx.x & 63) == 0) red[threadIdx.x >> 6] = part;
    __syncthreads();
    if (threadIdx.x == 0) out[g] = red[0] + red[1] + b2[0];
}

// ---------------- launch ----------------
extern "C" void kernel_launch(void* const* d_in, const int* in_sizes, int n_in,
                              void* d_out, int out_size, void* d_ws, size_t ws_size,
                              hipStream_t stream)
{
    const int*   x        = (const int*)d_in[0];
    const int*   ei       = (const int*)d_in[1];
    const int*   ea       = (const int*)d_in[2];
    const int*   batch    = (const int*)d_in[3];
    const float* node_emb = (const float*)d_in[4];
    const float* emb_w1   = (const float*)d_in[5];
    const float* emb_b1   = (const float*)d_in[6];
    const float* emb_g1   = (const float*)d_in[7];
    const float* emb_bt1  = (const float*)d_in[8];
    const float* emb_w2   = (const float*)d_in[9];
    const float* emb_b2   = (const float*)d_in[10];
    const float* bn0_g    = (const float*)d_in[11];
    const float* bn0_b    = (const float*)d_in[12];
    const float* Wq       = (const float*)d_in[13];
    const float* Wk       = (const float*)d_in[14];
    const float* Wv       = (const float*)d_in[15];
    const float* We       = (const float*)d_in[16];
    const float* att      = (const float*)d_in[17];
    const float* Wroot    = (const float*)d_in[18];
    const float* bias     = (const float*)d_in[19];
    const float* out_w1   = (const float*)d_in[20];
    const float* out_b1   = (const float*)d_in[21];
    const float* out_g1   = (const float*)d_in[22];
    const float* out_bt1  = (const float*)d_in[23];
    const float* out_w2   = (const float*)d_in[24];
    const float* out_b2   = (const float*)d_in[25];

    char* wp = (char*)d_ws;
    auto alloc = [&](size_t bytes) -> void* {
        void* p = (void*)wp;
        wp += (bytes + 255) & ~(size_t)255;
        return p;
    };
    float*          x0    = (float*)alloc((size_t)NN * HD * 4);
    unsigned short* x0b   = (unsigned short*)alloc((size_t)NN * HD * 2);
    unsigned short* hb0   = (unsigned short*)alloc((size_t)NN * HD * 2);
    unsigned short* hb1   = (unsigned short*)alloc((size_t)NN * HD * 2);
    unsigned short* hb2   = (unsigned short*)alloc((size_t)NN * HD * 2);
    unsigned short* hb3   = (unsigned short*)alloc((size_t)NN * HD * 2);
    unsigned short* QKVR  = (unsigned short*)alloc((size_t)NN * NCAT * 2);
    float*          x0tab = (float*)alloc((size_t)NVOC * HD * 4);
    unsigned short* etab  = (unsigned short*)alloc((size_t)NLAY * NVOC * CDIM * 2);
    unsigned short* Wpk   = (unsigned short*)alloc((size_t)NLAY * 224 * 64 * 8 * 2);
    int*   cnt   = (int*)alloc((size_t)NN * 4);
    int*   rowp  = (int*)alloc((size_t)(NN + 1) * 4);
    int*   wof   = (int*)alloc((size_t)(NN + 1) * 4);
    int*   part  = (int*)alloc((size_t)SNB * 4);
    int2*  cse   = (int2*)alloc((size_t)NE * 8);
    int*   gptr  = (int*)alloc((size_t)(NGR + 1) * 4);
    float* gsum  = (float*)alloc((size_t)NGR * 640 * 4);

    hipMemsetAsync(cnt, 0, (size_t)NN * 4, stream);

    k_tables_node<<<NVOC, 128, 0, stream>>>(node_emb, emb_w1, emb_b1, emb_g1, emb_bt1,
                                            emb_w2, emb_b2, bn0_g, bn0_b, x0tab);
    k_tables_edge<<<NLAY * NVOC, 256, 0, stream>>>(node_emb, We, etab);
    k_packw<<<NLAY * 224, 64, 0, stream>>>(Wq, Wk, Wv, Wroot, Wpk);
    k_hist_dst<<<(NE + 255) / 256, 256, 0, stream>>>(ei, cnt);
    k_blocksum<<<SNB, 256, 0, stream>>>(cnt, part);
    k_scanpart<<<1, 256, 0, stream>>>(part);
    k_csrwrite<<<SNB, 256, 0, stream>>>(cnt, part, rowp, wof);
    k_scatter<<<(NE + 255) / 256, 256, 0, stream>>>(ei, ea, wof, cse);
    k_gptr<<<(NGR + 1 + 255) / 256, 256, 0, stream>>>(batch, gptr);
    k_x0<<<(NN * 32 + 255) / 256, 256, 0, stream>>>(x, x0tab, x0, x0b);

    const unsigned short* hin = x0b;
    unsigned short* houts[NLAY] = {hb0, hb1, hb2, hb3};
    for (int l = 0; l < NLAY; ++l) {
        k_gemm<<<dim3((NN + 63) / 64, GP), 256, 0, stream>>>(
            hin, Wpk + (size_t)l * 224 * 512, QKVR);
        k_edge<<<(NN * 64 + 255) / 256, 256, 0, stream>>>(
            QKVR, etab + (size_t)l * NVOC * CDIM, att + (size_t)l * CDIM, bias + (size_t)l * HD,
            x0, rowp, cse, houts[l]);
        hin = houts[l];
    }
    k_poolall<<<NGR, 256, 0, stream>>>(x0b, hb0, hb1, hb2, hb3, gptr, gsum);
    k_out<<<NGR, 128, 0, stream>>>(gsum, gptr, out_w1, out_b1, out_g1, out_bt1,
                                   out_w2, out_b2, (float*)d_out);
}

// Round 7
// 476.543 us; speedup vs baseline: 1.3879x; 1.1360x over previous
//
#include <hip/hip_runtime.h>
#include <hip/hip_bf16.h>

#define NN 50000      // nodes
#define NE 200000     // edges
#define NGR 500       // graphs
#define HD 128        // hidden
#define CDIM 256      // H*DH
#define NLAY 4
#define NVOC 30
#define NCAT 896      // 256*3 + 128 : Q|K|V|R concatenated
#define SCH 256                       // scan chunk
#define SNB ((NN + SCH - 1) / SCH)    // 196 scan blocks
#define GP 4                          // gemm column panels
#define CBP (56 / GP)                 // cb iters per panel = 14

static constexpr float BN_INV = 0.9999950000374997f;  // 1/sqrt(1+1e-5)

typedef __attribute__((ext_vector_type(8))) short bf16x8;
typedef __attribute__((ext_vector_type(4))) float f32x4;

__device__ __forceinline__ float bf2f(unsigned short u) {
    return __uint_as_float(((unsigned)u) << 16);
}
__device__ __forceinline__ unsigned short f2bf(float f) {
    union { __hip_bfloat16 h; unsigned short u; } cv;
    cv.h = __float2bfloat16(f);
    return cv.u;
}

// ---------------- tables: x0table[30][128] = emb MLP (fp32) ----------------
__global__ __launch_bounds__(128) void k_tables_node(
    const float* __restrict__ ne, const float* __restrict__ w1, const float* __restrict__ b1,
    const float* __restrict__ g1, const float* __restrict__ bt1,
    const float* __restrict__ w2, const float* __restrict__ b2,
    const float* __restrict__ g0, const float* __restrict__ bt0,
    float* __restrict__ x0tab)
{
    int r = blockIdx.x, d = threadIdx.x;
    __shared__ float emb[HD], t1[HD];
    emb[d] = ne[r * HD + d];
    __syncthreads();
    float acc = b1[d];
    for (int k = 0; k < HD; ++k) acc += emb[k] * w1[k * HD + d];
    float t = fmaxf(acc * BN_INV * g1[d] + bt1[d], 0.f);
    t1[d] = t;
    __syncthreads();
    float acc2 = b2[d];
    for (int k = 0; k < HD; ++k) acc2 += t1[k] * w2[k * HD + d];
    x0tab[r * HD + d] = fmaxf(acc2 * BN_INV * g0[d] + bt0[d], 0.f);
}

// ---------------- tables: etab[l][30][256] bf16 = node_emb @ We[l] ----------------
__global__ __launch_bounds__(256) void k_tables_edge(
    const float* __restrict__ ne, const float* __restrict__ We, unsigned short* __restrict__ etab)
{
    int la = blockIdx.x;              // l*NVOC + a
    int l = la / NVOC, a = la % NVOC;
    int c = threadIdx.x;              // 0..255
    __shared__ float emb[HD];
    if (c < HD) emb[c] = ne[a * HD + c];
    __syncthreads();
    const float* W = We + (size_t)l * HD * CDIM;
    float acc = 0.f;
    for (int k = 0; k < HD; ++k) acc += emb[k] * W[k * CDIM + c];
    etab[(size_t)la * CDIM + c] = f2bf(acc);
}

// ---------------- pack weights: Wpk[l][kb][jb][lane][8] bf16 ----------------
// fragment map (both A and B operands share it): k = kb*32 + 8*(lane>>4) + t,
// j = jb*16 + (lane&15). cat columns: j<256 Wq | <512 Wk | <768 Wv | <896 Wroot
__global__ __launch_bounds__(64) void k_packw(
    const float* __restrict__ Wq, const float* __restrict__ Wk,
    const float* __restrict__ Wv, const float* __restrict__ Wr,
    unsigned short* __restrict__ Wpk)
{
    int b = blockIdx.x;               // l*224 + kb*56 + jb
    int l = b / 224, rem = b % 224;
    int kb = rem / 56, jb = rem % 56;
    int lane = threadIdx.x;
    int j = jb * 16 + (lane & 15);
    int kbase = kb * 32 + ((lane >> 4) << 3);
    unsigned short* dst = Wpk + ((size_t)b * 64 + lane) * 8;
#pragma unroll
    for (int t = 0; t < 8; ++t) {
        int k = kbase + t;
        float v;
        if (j < 256)       v = Wq[((size_t)l * HD + k) * CDIM + j];
        else if (j < 512)  v = Wk[((size_t)l * HD + k) * CDIM + (j - 256)];
        else if (j < 768)  v = Wv[((size_t)l * HD + k) * CDIM + (j - 512)];
        else               v = Wr[((size_t)l * HD + k) * HD + (j - 768)];
        dst[t] = f2bf(v);
    }
}

// ---------------- CSR build ----------------
__global__ void k_hist_dst(const int* __restrict__ ei, int* __restrict__ cnt)
{
    int e = blockIdx.x * blockDim.x + threadIdx.x;
    if (e < NE) atomicAdd(&cnt[ei[NE + e]], 1);
}

__global__ __launch_bounds__(256) void k_blocksum(const int* __restrict__ cnt, int* __restrict__ part)
{
    int t = threadIdx.x;
    int i = blockIdx.x * SCH + t;
    int v = (i < NN) ? cnt[i] : 0;
    __shared__ int sm[256];
    sm[t] = v;
    __syncthreads();
    for (int off = 128; off; off >>= 1) {
        if (t < off) sm[t] += sm[t + off];
        __syncthreads();
    }
    if (t == 0) part[blockIdx.x] = sm[0];
}

__global__ __launch_bounds__(256) void k_scanpart(int* __restrict__ part)
{
    int t = threadIdx.x;
    int v = (t < SNB) ? part[t] : 0;
    __shared__ int sm[256];
    sm[t] = v;
    __syncthreads();
    for (int off = 1; off < 256; off <<= 1) {
        int u = (t >= off) ? sm[t - off] : 0;
        __syncthreads();
        sm[t] += u;
        __syncthreads();
    }
    if (t < SNB) part[t] = sm[t] - v;   // exclusive
}

__global__ __launch_bounds__(256) void k_csrwrite(
    const int* __restrict__ cnt, const int* __restrict__ part,
    int* __restrict__ rowp, int* __restrict__ wof)
{
    int t = threadIdx.x;
    int i = blockIdx.x * SCH + t;
    int v = (i < NN) ? cnt[i] : 0;
    __shared__ int sm[256];
    sm[t] = v;
    __syncthreads();
    for (int off = 1; off < 256; off <<= 1) {
        int u = (t >= off) ? sm[t - off] : 0;
        __syncthreads();
        sm[t] += u;
        __syncthreads();
    }
    int excl = sm[t] - v + part[blockIdx.x];
    if (i < NN) { rowp[i] = excl; wof[i] = excl; }
    if (i == NN - 1) rowp[NN] = excl + v;   // = NE
}

// scatter (src, edge_attr) pairs into CSR order as int2
__global__ void k_scatter(const int* __restrict__ ei, const int* __restrict__ ea,
                          int* __restrict__ wof, int2* __restrict__ cse)
{
    int e = blockIdx.x * blockDim.x + threadIdx.x;
    if (e < NE) {
        int d = ei[NE + e];
        int pos = atomicAdd(&wof[d], 1);
        int2 v; v.x = ei[e]; v.y = ea[e];
        cse[pos] = v;
    }
}

__global__ void k_gptr(const int* __restrict__ batch, int* __restrict__ gptr)
{
    int g = blockIdx.x * blockDim.x + threadIdx.x;
    if (g > NGR) return;
    if (g == NGR) { gptr[g] = NN; return; }
    int lo = 0, hi = NN;
    while (lo < hi) { int mid = (lo + hi) >> 1; if (batch[mid] < g) lo = mid + 1; else hi = mid; }
    gptr[g] = lo;
}

// ---------------- x0[n] = x0table[x[n]] (fp32 + bf16) ----------------
__global__ void k_x0(const int* __restrict__ x, const float* __restrict__ tab,
                     float* __restrict__ x0, unsigned short* __restrict__ x0b)
{
    int idx = blockIdx.x * blockDim.x + threadIdx.x;  // NN*32 float4 slots
    if (idx >= NN * 32) return;
    int n = idx >> 5, c = idx & 31;
    float4 v = *(const float4*)&tab[x[n] * HD + c * 4];
    *(float4*)&x0[(size_t)n * HD + c * 4] = v;
    ushort4 u; u.x = f2bf(v.x); u.y = f2bf(v.y); u.z = f2bf(v.z); u.w = f2bf(v.w);
    *(ushort4*)&x0b[(size_t)n * HD + c * 4] = u;
}

// ---------------- bf16 MFMA GEMM (swapped operands): D[j][node] = (W^T h)^T ----
__global__ __launch_bounds__(256) void k_gemm(
    const unsigned short* __restrict__ Ab, const unsigned short* __restrict__ Wpk,
    unsigned short* __restrict__ C)
{
    int lane = threadIdx.x & 63, wid = threadIdx.x >> 6;
    int nb = (blockIdx.x * 4 + wid) * 16;
    int node = nb + (lane & 15);
    size_t arow = (size_t)((node < NN) ? node : (NN - 1));
    int ko = (lane >> 4) << 3;
    const unsigned short* ap = Ab + arow * HD + ko;
    bf16x8 b0 = *(const bf16x8*)(ap);
    bf16x8 b1 = *(const bf16x8*)(ap + 32);
    bf16x8 b2 = *(const bf16x8*)(ap + 64);
    bf16x8 b3 = *(const bf16x8*)(ap + 96);

    const unsigned short* wp = Wpk + (size_t)lane * 8;
    bool valid = node < NN;
    int jreg = (lane >> 4) << 2;            // j offset within the 16-col block
    unsigned short* cbase = C + (size_t)node * NCAT + jreg;
    int cb0 = blockIdx.y * CBP;
#pragma unroll 2
    for (int cb = cb0; cb < cb0 + CBP; ++cb) {
        const unsigned short* bp = wp + (size_t)cb * 512;
        bf16x8 w0 = *(const bf16x8*)(bp);
        bf16x8 w1 = *(const bf16x8*)(bp + 28672);   // kb stride = 56*512
        bf16x8 w2 = *(const bf16x8*)(bp + 57344);
        bf16x8 w3 = *(const bf16x8*)(bp + 86016);
        f32x4 acc = {0.f, 0.f, 0.f, 0.f};
        acc = __builtin_amdgcn_mfma_f32_16x16x32_bf16(w0, b0, acc, 0, 0, 0);
        acc = __builtin_amdgcn_mfma_f32_16x16x32_bf16(w1, b1, acc, 0, 0, 0);
        acc = __builtin_amdgcn_mfma_f32_16x16x32_bf16(w2, b2, acc, 0, 0, 0);
        acc = __builtin_amdgcn_mfma_f32_16x16x32_bf16(w3, b3, acc, 0, 0, 0);
        if (valid) {
            uint2 o;
            o.x = (unsigned)f2bf(acc[0]) | ((unsigned)f2bf(acc[1]) << 16);
            o.y = (unsigned)f2bf(acc[2]) | ((unsigned)f2bf(acc[3]) << 16);
            *(uint2*)(cbase + cb * 16) = o;
        }
    }
}

// ---------------- per-node attention: wave per dst node, 2-edge ILP -----------
// lane = head(1b) | sub(5b); 4 dims/lane. Softmax without max-subtraction (R5).
// Loop manually unrolled by 2 with INDEPENDENT accumulators: both edges' gather
// chains (cse -> K/V/etab) issue back-to-back -> 2x memory-level parallelism.
// R6 diagnosis: ~180 cyc/edge serial dependent-gather latency chain, VALUBusy
// 43% / HBM 30% / nothing saturated.
__global__ __launch_bounds__(256) void k_edge(
    const unsigned short* __restrict__ QKVR,  // [NN][896] bf16
    const unsigned short* __restrict__ etab,  // layer slice [30][256] bf16
    const float* __restrict__ attL, const float* __restrict__ biasL,
    const float* __restrict__ x0,
    const int* __restrict__ rowptr, const int2* __restrict__ cse,
    unsigned short* __restrict__ hb)          // [NN][128] bf16
{
    int n = (blockIdx.x * blockDim.x + threadIdx.x) >> 6;
    if (n >= NN) return;
    int lane = threadIdx.x & 63;
    int head = lane >> 5, sub = lane & 31;
    int col = head * HD + sub * 4;

    ushort4 qu = *(const ushort4*)&QKVR[(size_t)n * NCAT + col];
    float qx = bf2f(qu.x), qy = bf2f(qu.y), qz = bf2f(qu.z), qw = bf2f(qu.w);
    float4 a4 = *(const float4*)&attL[col];

    float l0 = 0.f, l1 = 0.f;
    float4 acc0 = {0.f, 0.f, 0.f, 0.f};
    float4 acc1 = {0.f, 0.f, 0.f, 0.f};

    int beg = rowptr[n], end = rowptr[n + 1];
    int idx = beg;
    for (; idx + 1 < end; idx += 2) {
        int2 seA = cse[idx];
        int2 seB = cse[idx + 1];
        const unsigned short* spA = QKVR + (size_t)seA.x * NCAT;
        const unsigned short* spB = QKVR + (size_t)seB.x * NCAT;
        ushort4 kuA = *(const ushort4*)&spA[256 + col];
        ushort4 kuB = *(const ushort4*)&spB[256 + col];
        ushort4 vuA = *(const ushort4*)&spA[512 + col];
        ushort4 vuB = *(const ushort4*)&spB[512 + col];
        ushort4 euA = *(const ushort4*)&etab[seA.y * CDIM + col];
        ushort4 euB = *(const ushort4*)&etab[seB.y * CDIM + col];

        float exA = bf2f(euA.x), eyA = bf2f(euA.y), ezA = bf2f(euA.z), ewA = bf2f(euA.w);
        float exB = bf2f(euB.x), eyB = bf2f(euB.y), ezB = bf2f(euB.z), ewB = bf2f(euB.w);

        float zxA = qx + bf2f(kuA.x) + exA; zxA = (zxA > 0.f) ? zxA : 0.2f * zxA;
        float zyA = qy + bf2f(kuA.y) + eyA; zyA = (zyA > 0.f) ? zyA : 0.2f * zyA;
        float zzA = qz + bf2f(kuA.z) + ezA; zzA = (zzA > 0.f) ? zzA : 0.2f * zzA;
        float zwA = qw + bf2f(kuA.w) + ewA; zwA = (zwA > 0.f) ? zwA : 0.2f * zwA;
        float zxB = qx + bf2f(kuB.x) + exB; zxB = (zxB > 0.f) ? zxB : 0.2f * zxB;
        float zyB = qy + bf2f(kuB.y) + eyB; zyB = (zyB > 0.f) ? zyB : 0.2f * zyB;
        float zzB = qz + bf2f(kuB.z) + ezB; zzB = (zzB > 0.f) ? zzB : 0.2f * zzB;
        float zwB = qw + bf2f(kuB.w) + ewB; zwB = (zwB > 0.f) ? zwB : 0.2f * zwB;

        float pA = zxA * a4.x + zyA * a4.y + zzA * a4.z + zwA * a4.w;
        float pB = zxB * a4.x + zyB * a4.y + zzB * a4.z + zwB * a4.w;
        pA += __shfl_xor(pA, 16); pB += __shfl_xor(pB, 16);
        pA += __shfl_xor(pA, 8);  pB += __shfl_xor(pB, 8);
        pA += __shfl_xor(pA, 4);  pB += __shfl_xor(pB, 4);
        pA += __shfl_xor(pA, 2);  pB += __shfl_xor(pB, 2);
        pA += __shfl_xor(pA, 1);  pB += __shfl_xor(pB, 1);
        float peA = __expf(fminf(fmaxf(pA, -30.f), 30.f));
        float peB = __expf(fminf(fmaxf(pB, -30.f), 30.f));

        acc0.x = fmaf(peA, bf2f(vuA.x) + exA, acc0.x);
        acc0.y = fmaf(peA, bf2f(vuA.y) + eyA, acc0.y);
        acc0.z = fmaf(peA, bf2f(vuA.z) + ezA, acc0.z);
        acc0.w = fmaf(peA, bf2f(vuA.w) + ewA, acc0.w);
        acc1.x = fmaf(peB, bf2f(vuB.x) + exB, acc1.x);
        acc1.y = fmaf(peB, bf2f(vuB.y) + eyB, acc1.y);
        acc1.z = fmaf(peB, bf2f(vuB.z) + ezB, acc1.z);
        acc1.w = fmaf(peB, bf2f(vuB.w) + ewB, acc1.w);
        l0 += peA;
        l1 += peB;
    }
    if (idx < end) {
        int2 se = cse[idx];
        const unsigned short* sp = QKVR + (size_t)se.x * NCAT;
        ushort4 ku = *(const ushort4*)&sp[256 + col];
        ushort4 vu = *(const ushort4*)&sp[512 + col];
        ushort4 eu = *(const ushort4*)&etab[se.y * CDIM + col];
        float ex = bf2f(eu.x), ey = bf2f(eu.y), ez = bf2f(eu.z), ew = bf2f(eu.w);
        float zx = qx + bf2f(ku.x) + ex; zx = (zx > 0.f) ? zx : 0.2f * zx;
        float zy = qy + bf2f(ku.y) + ey; zy = (zy > 0.f) ? zy : 0.2f * zy;
        float zz = qz + bf2f(ku.z) + ez; zz = (zz > 0.f) ? zz : 0.2f * zz;
        float zw = qw + bf2f(ku.w) + ew; zw = (zw > 0.f) ? zw : 0.2f * zw;
        float p = zx * a4.x + zy * a4.y + zz * a4.z + zw * a4.w;
        p += __shfl_xor(p, 16); p += __shfl_xor(p, 8);
        p += __shfl_xor(p, 4);  p += __shfl_xor(p, 2); p += __shfl_xor(p, 1);
        float pe = __expf(fminf(fmaxf(p, -30.f), 30.f));
        acc0.x = fmaf(pe, bf2f(vu.x) + ex, acc0.x);
        acc0.y = fmaf(pe, bf2f(vu.y) + ey, acc0.y);
        acc0.z = fmaf(pe, bf2f(vu.z) + ez, acc0.z);
        acc0.w = fmaf(pe, bf2f(vu.w) + ew, acc0.w);
        l0 += pe;
    }
    float l = l0 + l1;
    float invl = (l > 0.f) ? 1.0f / l : 0.f;
    float ax = (acc0.x + acc1.x) * invl, ay = (acc0.y + acc1.y) * invl;
    float az = (acc0.z + acc1.z) * invl, aw = (acc0.w + acc1.w) * invl;
    // mean over heads: pair lane <-> lane^32
    ax = 0.5f * (ax + __shfl_xor(ax, 32));
    ay = 0.5f * (ay + __shfl_xor(ay, 32));
    az = 0.5f * (az + __shfl_xor(az, 32));
    aw = 0.5f * (aw + __shfl_xor(aw, 32));
    if (head == 0) {
        ushort4 ru = *(const ushort4*)&QKVR[(size_t)n * NCAT + 768 + sub * 4];
        float4 b4 = *(const float4*)&biasL[sub * 4];
        float4 x4 = *(const float4*)&x0[(size_t)n * HD + sub * 4];
        float ox = 0.9f * fmaxf(ax + bf2f(ru.x) + b4.x, 0.f) + 0.1f * x4.x;
        float oy = 0.9f * fmaxf(ay + bf2f(ru.y) + b4.y, 0.f) + 0.1f * x4.y;
        float oz = 0.9f * fmaxf(az + bf2f(ru.z) + b4.z, 0.f) + 0.1f * x4.z;
        float ow = 0.9f * fmaxf(aw + bf2f(ru.w) + b4.w, 0.f) + 0.1f * x4.w;
        ushort4 o; o.x = f2bf(ox); o.y = f2bf(oy); o.z = f2bf(oz); o.w = f2bf(ow);
        *(ushort4*)&hb[(size_t)n * HD + sub * 4] = o;
    }
}

// ---------------- pooling: grid (graph, slice), vectorized uint2 loads --------
__global__ __launch_bounds__(256) void k_poolall(
    const unsigned short* __restrict__ x0b,
    const unsigned short* __restrict__ h0, const unsigned short* __restrict__ h1,
    const unsigned short* __restrict__ h2, const unsigned short* __restrict__ h3,
    const int* __restrict__ gptr, float* __restrict__ gsum)
{
    int g = blockIdx.x, sl = blockIdx.y;
    const unsigned short* src = (sl == 0) ? x0b : (sl == 1) ? h0 : (sl == 2) ? h1
                              : (sl == 3) ? h2 : h3;
    int q = threadIdx.x & 31;     // dim quad: dims q*4 .. q*4+3
    int r = threadIdx.x >> 5;     // row group 0..7
    int beg = gptr[g], end = gptr[g + 1];
    float sx = 0.f, sy = 0.f, sz = 0.f, sw = 0.f;
    for (int n = beg + r; n < end; n += 8) {
        uint2 u = *(const uint2*)&src[(size_t)n * HD + q * 4];
        sx += __uint_as_float(u.x << 16);
        sy += __uint_as_float(u.x & 0xffff0000u);
        sz += __uint_as_float(u.y << 16);
        sw += __uint_as_float(u.y & 0xffff0000u);
    }
    __shared__ float4 sm[8][32];
    float4 s4 = {sx, sy, sz, sw};
    sm[r][q] = s4;
    __syncthreads();
    if (r == 0) {
        float4 t = sm[0][q];
#pragma unroll
        for (int j = 1; j < 8; ++j) {
            float4 u = sm[j][q];
            t.x += u.x; t.y += u.y; t.z += u.z; t.w += u.w;
        }
        *(float4*)&gsum[(size_t)g * 640 + sl * HD + q * 4] = t;
    }
}

// ---------------- final MLP: g[640] -> 128 -> 1 ----------------
__global__ __launch_bounds__(128) void k_out(
    const float* __restrict__ gsum, const int* __restrict__ gptr,
    const float* __restrict__ w1, const float* __restrict__ b1,
    const float* __restrict__ g1, const float* __restrict__ bt1,
    const float* __restrict__ w2, const float* __restrict__ b2,
    float* __restrict__ out)
{
    int g = blockIdx.x, d = threadIdx.x;
    __shared__ float row[640];
    __shared__ float red[2];
    int c = gptr[g + 1] - gptr[g];
    float invc = 1.0f / (float)max(c, 1);
    for (int j = d; j < 640; j += 128) row[j] = gsum[(size_t)g * 640 + j] * invc;
    __syncthreads();
    float acc = b1[d];
    for (int j = 0; j < 640; ++j) acc += row[j] * w1[j * HD + d];
    float val = fmaxf(acc * BN_INV * g1[d] + bt1[d], 0.f);
    float part = val * w2[d];
    part += __shfl_xor(part, 32); part += __shfl_xor(part, 16);
    part += __shfl_xor(part, 8);  part += __shfl_xor(part, 4);
    part += __shfl_xor(part, 2);  part += __shfl_xor(part, 1);
    if ((threadIdx.x & 63) == 0) red[threadIdx.x >> 6] = part;
    __syncthreads();
    if (threadIdx.x == 0) out[g] = red[0] + red[1] + b2[0];
}

// ---------------- launch ----------------
extern "C" void kernel_launch(void* const* d_in, const int* in_sizes, int n_in,
                              void* d_out, int out_size, void* d_ws, size_t ws_size,
                              hipStream_t stream)
{
    const int*   x        = (const int*)d_in[0];
    const int*   ei       = (const int*)d_in[1];
    const int*   ea       = (const int*)d_in[2];
    const int*   batch    = (const int*)d_in[3];
    const float* node_emb = (const float*)d_in[4];
    const float* emb_w1   = (const float*)d_in[5];
    const float* emb_b1   = (const float*)d_in[6];
    const float* emb_g1   = (const float*)d_in[7];
    const float* emb_bt1  = (const float*)d_in[8];
    const float* emb_w2   = (const float*)d_in[9];
    const float* emb_b2   = (const float*)d_in[10];
    const float* bn0_g    = (const float*)d_in[11];
    const float* bn0_b    = (const float*)d_in[12];
    const float* Wq       = (const float*)d_in[13];
    const float* Wk       = (const float*)d_in[14];
    const float* Wv       = (const float*)d_in[15];
    const float* We       = (const float*)d_in[16];
    const float* att      = (const float*)d_in[17];
    const float* Wroot    = (const float*)d_in[18];
    const float* bias     = (const float*)d_in[19];
    const float* out_w1   = (const float*)d_in[20];
    const float* out_b1   = (const float*)d_in[21];
    const float* out_g1   = (const float*)d_in[22];
    const float* out_bt1  = (const float*)d_in[23];
    const float* out_w2   = (const float*)d_in[24];
    const float* out_b2   = (const float*)d_in[25];

    char* wp = (char*)d_ws;
    auto alloc = [&](size_t bytes) -> void* {
        void* p = (void*)wp;
        wp += (bytes + 255) & ~(size_t)255;
        return p;
    };
    float*          x0    = (float*)alloc((size_t)NN * HD * 4);
    unsigned short* x0b   = (unsigned short*)alloc((size_t)NN * HD * 2);
    unsigned short* hb0   = (unsigned short*)alloc((size_t)NN * HD * 2);
    unsigned short* hb1   = (unsigned short*)alloc((size_t)NN * HD * 2);
    unsigned short* hb2   = (unsigned short*)alloc((size_t)NN * HD * 2);
    unsigned short* hb3   = (unsigned short*)alloc((size_t)NN * HD * 2);
    unsigned short* QKVR  = (unsigned short*)alloc((size_t)NN * NCAT * 2);
    float*          x0tab = (float*)alloc((size_t)NVOC * HD * 4);
    unsigned short* etab  = (unsigned short*)alloc((size_t)NLAY * NVOC * CDIM * 2);
    unsigned short* Wpk   = (unsigned short*)alloc((size_t)NLAY * 224 * 64 * 8 * 2);
    int*   cnt   = (int*)alloc((size_t)NN * 4);
    int*   rowp  = (int*)alloc((size_t)(NN + 1) * 4);
    int*   wof   = (int*)alloc((size_t)(NN + 1) * 4);
    int*   part  = (int*)alloc((size_t)SNB * 4);
    int2*  cse   = (int2*)alloc((size_t)NE * 8);
    int*   gptr  = (int*)alloc((size_t)(NGR + 1) * 4);
    float* gsum  = (float*)alloc((size_t)NGR * 640 * 4);

    hipMemsetAsync(cnt, 0, (size_t)NN * 4, stream);

    k_tables_node<<<NVOC, 128, 0, stream>>>(node_emb, emb_w1, emb_b1, emb_g1, emb_bt1,
                                            emb_w2, emb_b2, bn0_g, bn0_b, x0tab);
    k_tables_edge<<<NLAY * NVOC, 256, 0, stream>>>(node_emb, We, etab);
    k_packw<<<NLAY * 224, 64, 0, stream>>>(Wq, Wk, Wv, Wroot, Wpk);
    k_hist_dst<<<(NE + 255) / 256, 256, 0, stream>>>(ei, cnt);
    k_blocksum<<<SNB, 256, 0, stream>>>(cnt, part);
    k_scanpart<<<1, 256, 0, stream>>>(part);
    k_csrwrite<<<SNB, 256, 0, stream>>>(cnt, part, rowp, wof);
    k_scatter<<<(NE + 255) / 256, 256, 0, stream>>>(ei, ea, wof, cse);
    k_gptr<<<(NGR + 1 + 255) / 256, 256, 0, stream>>>(batch, gptr);
    k_x0<<<(NN * 32 + 255) / 256, 256, 0, stream>>>(x, x0tab, x0, x0b);

    const unsigned short* hin = x0b;
    unsigned short* houts[NLAY] = {hb0, hb1, hb2, hb3};
    for (int l = 0; l < NLAY; ++l) {
        k_gemm<<<dim3((NN + 63) / 64, GP), 256, 0, stream>>>(
            hin, Wpk + (size_t)l * 224 * 512, QKVR);
        k_edge<<<(NN * 64 + 255) / 256, 256, 0, stream>>>(
            QKVR, etab + (size_t)l * NVOC * CDIM, att + (size_t)l * CDIM, bias + (size_t)l * HD,
            x0, rowp, cse, houts[l]);
        hin = houts[l];
    }
    k_poolall<<<dim3(NGR, 5), 256, 0, stream>>>(x0b, hb0, hb1, hb2, hb3, gptr, gsum);
    k_out<<<NGR, 128, 0, stream>>>(gsum, gptr, out_w1, out_b1, out_g1, out_bt1,
                                   out_w2, out_b2, (float*)d_out);
}